// Round 3
// baseline (700.678 us; speedup 1.0000x reference)
//
#include <hip/hip_runtime.h>

// ---------------------------------------------------------------------------
// ExtraPositionPromptSABottleneck on MI355X (gfx950)
// B=8, DIMS=512, C=256, H=W=64, N=4096.
//
// Round 7:
//  - gemm_core rewritten as prefetch double-buffer (T3-minimum schedule):
//    ONE __syncthreads per K-step; tile t+1's global_load_lds are in flight
//    while tile t's ds_read+MFMA run.  Round-6 evidence: halving K changed
//    nothing -> the old 2-barrier zero-overlap loop was pure exposed latency.
//  - gemm4b was 256 blocks = 1 block/CU (no TLP).  Split-K=2: 512 blocks,
//    2/CU, bf16 unscaled partials -> new reduce4 kernel adds partials and
//    applies 1/lsum (scaling moved out of gemm4b).
//  - Keeps round-6 algebra: pos -> rhwT, gemm3b K=256, register pos-add.
// ---------------------------------------------------------------------------

typedef __bf16 bf16;
typedef __attribute__((ext_vector_type(8))) __bf16 bf16x8;
typedef __attribute__((ext_vector_type(4))) __bf16 bf16x4;
typedef __attribute__((ext_vector_type(4))) float f32x4;

__device__ __forceinline__ float silu_f(float x) { return x / (1.f + __expf(-x)); }

__device__ __forceinline__ void zero_acc(f32x4 (&acc)[4][4])
{
#pragma unroll
    for (int i = 0; i < 4; ++i)
#pragma unroll
        for (int j = 0; j < 4; ++j)
            acc[i][j] = (f32x4){0.f, 0.f, 0.f, 0.f};
}

__device__ __forceinline__ void load_lds16(const bf16* g, bf16* l)
{
    __builtin_amdgcn_global_load_lds(
        (const __attribute__((address_space(1))) unsigned int*)g,
        (__attribute__((address_space(3))) unsigned int*)l, 16, 0, 0);
}

// ---- prefetch double-buffered GEMM core: block 256 thr, tile 128x128, BK=32
// A: block's 128 rows, k-contig stride lda. B: block's 128 "cols", stride ldb.
// LDS slot (row, kb) holds global (row, kb ^ ((row>>1)&3)) -- XOR swizzle.
// Schedule per iter: [barrier: buf[cur] loads drained, prev reads done] ->
// issue tile t+1 loads into buf[cur^1] -> ds_read+MFMA on buf[cur].
__device__ __forceinline__ void gemm_core_db(
    const bf16* __restrict__ A, int lda,
    const bf16* __restrict__ B, int ldb,
    int K, f32x4 (&acc)[4][4])
{
    __shared__ bf16 As[2][128 * 32];
    __shared__ bf16 Bs[2][128 * 32];
    const int tid = threadIdx.x;
    const int wave = tid >> 6;
    const int lane = tid & 63;
    const int lm = lane & 15;
    const int kq = lane >> 4;
    const int m0 = (wave >> 1) * 64;
    const int n0 = (wave & 1) * 64;
    // staging: each thread supplies 16B per round; 2 rounds per matrix.
    const int srow = tid >> 2;                              // rows 0..63, +64
    const int skoff = (((tid & 3) ^ ((tid >> 3) & 3))) * 8; // swizzled k-block
    const int krd = (kq ^ ((lm >> 1) & 3)) * 8;             // read-side offset
    zero_acc(acc);
    const bf16* ga = A + (size_t)srow * lda + skoff;
    const bf16* gb = B + (size_t)srow * ldb + skoff;
    // prologue: stage tile 0 into buffer 0
    load_lds16(ga, As[0] + tid * 8);
    load_lds16(ga + (size_t)64 * lda, As[0] + tid * 8 + 64 * 32);
    load_lds16(gb, Bs[0] + tid * 8);
    load_lds16(gb + (size_t)64 * ldb, Bs[0] + tid * 8 + 64 * 32);
    const int nt = K >> 5;
    int cur = 0;
    for (int t = 0; t < nt; ++t) {
        __syncthreads();   // drains vmcnt -> buf[cur] ready; prev reads done
        if (t + 1 < nt) {
            const bf16* na = ga + (t + 1) * 32;
            const bf16* nb = gb + (t + 1) * 32;
            bf16* dA = As[cur ^ 1] + tid * 8;
            bf16* dB = Bs[cur ^ 1] + tid * 8;
            load_lds16(na, dA);
            load_lds16(na + (size_t)64 * lda, dA + 64 * 32);
            load_lds16(nb, dB);
            load_lds16(nb + (size_t)64 * ldb, dB + 64 * 32);
        }
        const bf16* as = As[cur];
        const bf16* bs = Bs[cur];
        bf16x8 av[4], bv[4];
#pragma unroll
        for (int tt = 0; tt < 4; ++tt)
            av[tt] = *(const bf16x8*)(as + (m0 + tt * 16 + lm) * 32 + krd);
#pragma unroll
        for (int tt = 0; tt < 4; ++tt)
            bv[tt] = *(const bf16x8*)(bs + (n0 + tt * 16 + lm) * 32 + krd);
#pragma unroll
        for (int i = 0; i < 4; ++i)
#pragma unroll
            for (int j = 0; j < 4; ++j)
                acc[i][j] = __builtin_amdgcn_mfma_f32_16x16x32_bf16(
                    av[i], bv[j], acc[i][j], 0, 0, 0);
        cur ^= 1;
    }
}

// ------------------------------ prep kernels -------------------------------

__global__ __launch_bounds__(256) void prep_misc_kernel(
    const float* __restrict__ cv1_w,
    const float* __restrict__ qw, const float* __restrict__ qb,
    const float* __restrict__ kw, const float* __restrict__ kb,
    const float* __restrict__ vw, const float* __restrict__ vb,
    const float* __restrict__ ew, const float* __restrict__ eb,
    const float* __restrict__ cv2_w,
    const float* __restrict__ g1, const float* __restrict__ b1,
    const float* __restrict__ m1, const float* __restrict__ v1,
    const float* __restrict__ g2, const float* __restrict__ b2,
    const float* __restrict__ m2, const float* __restrict__ v2,
    const float* __restrict__ rel_h, const float* __restrict__ rel_w,
    bf16* __restrict__ w1b, bf16* __restrict__ wqkve, bf16* __restrict__ w2b,
    bf16* __restrict__ posT,
    float* __restrict__ biasq,
    float* __restrict__ bn1s, float* __restrict__ bn1h,
    float* __restrict__ bn2s, float* __restrict__ bn2h)
{
    int idx = blockIdx.x * 256 + threadIdx.x;
    if (idx < 131072) { w1b[idx] = (bf16)cv1_w[idx]; return; }
    idx -= 131072;
    if (idx < 262144) {
        int j = idx >> 8, c = idx & 255;
        int p = j >> 8, r = j & 255;
        const float* w = (p == 0) ? qw : (p == 1) ? kw : (p == 2) ? vw : ew;
        wqkve[idx] = (bf16)w[r * 256 + c];
        return;
    }
    idx -= 262144;
    if (idx < 131072) { w2b[idx] = (bf16)cv2_w[idx]; return; }
    idx -= 131072;
    if (idx < 1024) {
        int p = idx >> 8, r = idx & 255;
        const float* bb = (p == 0) ? qb : (p == 1) ? kb : (p == 2) ? vb : eb;
        biasq[idx] = bb[r];
        return;
    }
    idx -= 1024;
    if (idx < 256) {
        float s = g1[idx] * rsqrtf(v1[idx] + 1e-5f);
        bn1s[idx] = s;
        bn1h[idx] = b1[idx] - m1[idx] * s;
        return;
    }
    idx -= 256;
    if (idx < 512) {
        float s = g2[idx] * rsqrtf(v2[idx] + 1e-5f);
        bn2s[idx] = s;
        bn2h[idx] = b2[idx] - m2[idx] * s;
        return;
    }
    idx -= 512;
    if (idx < 32768) {
        // posT[r][c], r<64: rel_h[c][r]; r>=64: rel_w[c][r-64]
        int r = idx >> 8, c = idx & 255;
        posT[idx] = (bf16)((r < 64) ? rel_h[c * 64 + r] : rel_w[c * 64 + (r - 64)]);
        return;
    }
}

__global__ __launch_bounds__(256) void zero_lsum_kernel(float* __restrict__ p)
{
    p[blockIdx.x * 256 + threadIdx.x] = 0.f;
}

// xt[b*4096+n][d] = (bf16) x[b][d][n]
__global__ __launch_bounds__(256) void transpose_x_kernel(
    const float* __restrict__ x, bf16* __restrict__ xt)
{
    __shared__ float tile[64][65];
    int b = blockIdx.z;
    int n0 = blockIdx.x * 64;
    int d0 = blockIdx.y * 64;
    int tx = threadIdx.x & 63, ty = threadIdx.x >> 6;
#pragma unroll
    for (int i = 0; i < 16; ++i) {
        int d = i * 4 + ty;
        tile[d][tx] = x[((size_t)(b * 512 + d0 + d)) * 4096 + n0 + tx];
    }
    __syncthreads();
#pragma unroll
    for (int i = 0; i < 16; ++i) {
        int n = i * 4 + ty;
        xt[((size_t)(b * 4096 + n0 + n)) * 512 + d0 + tx] = (bf16)tile[tx][n];
    }
}

// v_cm[b][c][m] = v_nm[b*4096+m][c]
__global__ __launch_bounds__(256) void transpose_v_kernel(
    const bf16* __restrict__ v_nm, bf16* __restrict__ v_cm)
{
    __shared__ float tile[64][65];
    int b = blockIdx.z;
    int m0 = blockIdx.x * 64;
    int c0 = blockIdx.y * 64;
    int tx = threadIdx.x & 63, ty = threadIdx.x >> 6;
#pragma unroll
    for (int i = 0; i < 16; ++i) {
        int m = i * 4 + ty;
        tile[m][tx] = (float)v_nm[((size_t)(b * 4096 + m0 + m)) * 256 + c0 + tx];
    }
    __syncthreads();
#pragma unroll
    for (int i = 0; i < 16; ++i) {
        int c = i * 4 + ty;
        v_cm[((size_t)(b * 256 + c0 + c)) * 4096 + m0 + tx] = (bf16)tile[tx][c];
    }
}

// ------------------------------ GEMM kernels -------------------------------

// x1t[row][col] = silu(bn1( sum_d xt[row][d] * w1b[col][d] ))
__global__ __launch_bounds__(256) void gemm1_kernel(
    const bf16* __restrict__ xt, const bf16* __restrict__ w1b,
    const float* __restrict__ bn1s, const float* __restrict__ bn1h,
    bf16* __restrict__ x1t)
{
    const bf16* A = xt + (size_t)(blockIdx.y * 128) * 512;
    const bf16* Bm = w1b + (size_t)(blockIdx.x * 128) * 512;
    f32x4 acc[4][4];
    gemm_core_db(A, 512, Bm, 512, 512, acc);
    int wave = threadIdx.x >> 6;
    int lane = threadIdx.x & 63;
    int m0 = blockIdx.y * 128 + (wave >> 1) * 64;
    int n0 = blockIdx.x * 128 + (wave & 1) * 64;
    int lm = lane & 15, kq = lane >> 4;
#pragma unroll
    for (int i = 0; i < 4; ++i)
#pragma unroll
        for (int j = 0; j < 4; ++j)
#pragma unroll
            for (int r = 0; r < 4; ++r) {
                int row = m0 + i * 16 + kq * 4 + r;
                int col = n0 + j * 16 + lm;
                float h = bn1s[col] * acc[i][j][r] + bn1h[col];
                x1t[(size_t)row * 256 + col] = (bf16)silu_f(h);
            }
}

// projections: col<512 -> qk[.][col]; <768 -> v_nm[.][col-512]; else e_nm
__global__ __launch_bounds__(256) void gemm2_kernel(
    const bf16* __restrict__ x1t, const bf16* __restrict__ wqkve,
    const float* __restrict__ biasq,
    bf16* __restrict__ qk, bf16* __restrict__ v_nm, bf16* __restrict__ e_nm)
{
    const bf16* A = x1t + (size_t)(blockIdx.y * 128) * 256;
    const bf16* Bm = wqkve + (size_t)(blockIdx.x * 128) * 256;
    f32x4 acc[4][4];
    gemm_core_db(A, 256, Bm, 256, 256, acc);
    int wave = threadIdx.x >> 6;
    int lane = threadIdx.x & 63;
    int m0 = blockIdx.y * 128 + (wave >> 1) * 64;
    int n0 = blockIdx.x * 128 + (wave & 1) * 64;
    int lm = lane & 15, kq = lane >> 4;
#pragma unroll
    for (int i = 0; i < 4; ++i)
#pragma unroll
        for (int j = 0; j < 4; ++j)
#pragma unroll
            for (int r = 0; r < 4; ++r) {
                int row = m0 + i * 16 + kq * 4 + r;
                int col = n0 + j * 16 + lm;
                bf16 val = (bf16)(acc[i][j][r] + biasq[col]);
                if (col < 512)       qk[(size_t)row * 512 + col] = val;
                else if (col < 768)  v_nm[(size_t)row * 256 + (col - 512)] = val;
                else                 e_nm[(size_t)row * 256 + (col - 768)] = val;
            }
}

// rhwT[b][m][r] = sum_c posT[r][c] * e_nm[b*4096+m][c]  (r<64: RH, r>=64: RW)
__global__ __launch_bounds__(256) void gemm_rhw_kernel(
    const bf16* __restrict__ posT, const bf16* __restrict__ e_nm,
    bf16* __restrict__ rhwT)
{
    int b = blockIdx.z;
    const bf16* A = e_nm + ((size_t)b * 4096 + blockIdx.x * 128) * 256;
    f32x4 acc[4][4];
    gemm_core_db(A, 256, posT, 256, 256, acc);
    int wave = threadIdx.x >> 6;
    int lane = threadIdx.x & 63;
    int m0 = (wave >> 1) * 64, n0 = (wave & 1) * 64;
    int lm = lane & 15, kq = lane >> 4;
    bf16* rb = rhwT + ((size_t)b * 4096 + blockIdx.x * 128) * 128;
#pragma unroll
    for (int i = 0; i < 4; ++i)
#pragma unroll
        for (int j = 0; j < 4; ++j)
#pragma unroll
            for (int r = 0; r < 4; ++r)
                rb[(size_t)(m0 + i * 16 + kq * 4 + r) * 128 + n0 + j * 16 + lm] =
                    (bf16)acc[i][j][r];
}

// P[bz][n][m] = exp(q[b,n,:].k[b,m,:] + RH[h_n,m] + RW[w_n,m] - 8), bf16;
// row sums -> lsum[bz][n]
__global__ __launch_bounds__(256) void gemm3b_kernel(
    const bf16* __restrict__ qk, const bf16* __restrict__ rhwT,
    bf16* __restrict__ P, float* __restrict__ lsum, int gbase)
{
    __shared__ float rs[128];
    // XCD-aware bijective swizzle (4096 blocks, %8==0): each XCD gets a
    // contiguous 512-block chunk -> qk slice fits per-XCD 4MB L2.
    int flat = blockIdx.x + 32 * blockIdx.y + 1024 * blockIdx.z;
    flat = (flat & 7) * 512 + (flat >> 3);
    const int bx = flat & 31, by = (flat >> 5) & 31, bz = flat >> 10;
    const int b = gbase + bz;
    const int tid = threadIdx.x;
    const int wave = tid >> 6;
    const int lane = tid & 63;
    const int m0 = (wave >> 1) * 64, n0 = (wave & 1) * 64;
    const int lm = lane & 15, kq = lane >> 4;
    // ---- positional terms -> registers (L2-hot, vectorized), issued early
    // so the K-loop hides their latency.
    float rhv[4];
    bf16x4 rwv[4][4]; // [j][i]
    {
        const bf16* rbT = rhwT + ((size_t)b * 4096 + bx * 128) * 128;
        const int hidx = 2 * by + (m0 >> 6);
#pragma unroll
        for (int j = 0; j < 4; ++j) {
            const bf16* cp = rbT + (size_t)(n0 + j * 16 + lm) * 128;
            rhv[j] = (float)cp[hidx];
#pragma unroll
            for (int i = 0; i < 4; ++i)
                rwv[j][i] = *(const bf16x4*)(cp + 64 + i * 16 + kq * 4);
        }
    }
    const bf16* A = qk + ((size_t)b * 4096 + by * 128) * 512;
    const bf16* Bm = qk + ((size_t)b * 4096 + bx * 128) * 512 + 256;
    f32x4 acc[4][4];
    gemm_core_db(A, 512, Bm, 512, 256, acc);
    if (tid < 128) rs[tid] = 0.f;
    __syncthreads();
    // add positional terms, exp, per-lane row partials
    float ps[4][4];
#pragma unroll
    for (int i = 0; i < 4; ++i)
#pragma unroll
        for (int r = 0; r < 4; ++r) {
            float s = 0.f;
#pragma unroll
            for (int j = 0; j < 4; ++j) {
                float sv = acc[i][j][r] + rhv[j] + (float)rwv[j][i][r];
                float e = __expf(sv - 8.f);
                acc[i][j][r] = e;
                s += e;
            }
            ps[i][r] = s;
        }
    // butterfly over the 16-lane lm group (covers the wave's 64 cols)
#pragma unroll
    for (int msk = 1; msk < 16; msk <<= 1)
#pragma unroll
        for (int i = 0; i < 4; ++i)
#pragma unroll
            for (int r = 0; r < 4; ++r)
                ps[i][r] += __shfl_xor(ps[i][r], msk);
    if (lm == 0) {
#pragma unroll
        for (int i = 0; i < 4; ++i)
#pragma unroll
            for (int r = 0; r < 4; ++r)
                atomicAdd(&rs[m0 + i * 16 + kq * 4 + r], ps[i][r]);
    }
    // store exp(S) tile
    bf16* Pb = P + ((size_t)bz * 4096 + by * 128) * 4096 + bx * 128;
#pragma unroll
    for (int i = 0; i < 4; ++i)
#pragma unroll
        for (int j = 0; j < 4; ++j)
#pragma unroll
            for (int r = 0; r < 4; ++r)
                Pb[(size_t)(m0 + i * 16 + kq * 4 + r) * 4096 + n0 + j * 16 + lm] =
                    (bf16)acc[i][j][r];
    __syncthreads();
    if (tid < 128)
        atomicAdd(&lsum[(size_t)bz * 4096 + by * 128 + tid], rs[tid]);
}

// split-K=2 PV: pacc[kc][bz*4096+n][c] = sum_{m in chunk} P[bz][n][m]*v_cm[b][c][m]
__global__ __launch_bounds__(256) void gemm4b_kernel(
    const bf16* __restrict__ P, const bf16* __restrict__ v_cm,
    bf16* __restrict__ pacc, int gbase)
{
    int bz = blockIdx.z >> 1;
    int kc = blockIdx.z & 1;
    int b = gbase + bz;
    const bf16* A = P + ((size_t)bz * 4096 + blockIdx.y * 128) * 4096 + kc * 2048;
    const bf16* Bm = v_cm + ((size_t)b * 256 + blockIdx.x * 128) * 4096 + kc * 2048;
    f32x4 acc[4][4];
    gemm_core_db(A, 4096, Bm, 4096, 2048, acc);
    int wave = threadIdx.x >> 6;
    int lane = threadIdx.x & 63;
    int m0 = (wave >> 1) * 64, n0 = (wave & 1) * 64;
    int lm = lane & 15, kq = lane >> 4;
    bf16* ob = pacc + (((size_t)kc * 16384 + bz * 4096 + blockIdx.y * 128)) * 256
             + blockIdx.x * 128;
#pragma unroll
    for (int i = 0; i < 4; ++i)
#pragma unroll
        for (int r = 0; r < 4; ++r)
#pragma unroll
            for (int j = 0; j < 4; ++j)
                ob[(size_t)(m0 + i * 16 + kq * 4 + r) * 256 + n0 + j * 16 + lm] =
                    (bf16)acc[i][j][r];
}

// out_t[(gbase*4096)+row][c] = (pacc[0][row][c]+pacc[1][row][c]) / lsum[row]
__global__ __launch_bounds__(256) void reduce4_kernel(
    const bf16* __restrict__ pacc, const float* __restrict__ lsum,
    bf16* __restrict__ out_t, int gbase)
{
    int t = blockIdx.x * 256 + threadIdx.x;   // 524288 threads
    int row = t >> 5;                          // bz*4096+n, 0..16383
    int c0 = (t & 31) * 8;
    bf16x8 p0 = *(const bf16x8*)(pacc + (size_t)row * 256 + c0);
    bf16x8 p1 = *(const bf16x8*)(pacc + (size_t)(16384 + row) * 256 + c0);
    float inv = 1.f / lsum[row];
    bf16x8 o;
#pragma unroll
    for (int e = 0; e < 8; ++e)
        o[e] = (bf16)(((float)p0[e] + (float)p1[e]) * inv);
    *(bf16x8*)(out_t + ((size_t)gbase * 4096 + row) * 256 + c0) = o;
}

// d_out[b][d][n] = x[b][d][n] + silu(bn2( sum_c w2b[d][c]*out_t[b*4096+n][c] ))
__global__ __launch_bounds__(256) void gemm5_kernel(
    const bf16* __restrict__ w2b, const bf16* __restrict__ out_t,
    const float* __restrict__ bn2s, const float* __restrict__ bn2h,
    const float* __restrict__ x, float* __restrict__ out)
{
    int b = blockIdx.z;
    const bf16* A = w2b + (size_t)(blockIdx.y * 128) * 256;
    const bf16* Bm = out_t + ((size_t)b * 4096 + blockIdx.x * 128) * 256;
    f32x4 acc[4][4];
    gemm_core_db(A, 256, Bm, 256, 256, acc);
    int wave = threadIdx.x >> 6;
    int lane = threadIdx.x & 63;
    int m0 = blockIdx.y * 128 + (wave >> 1) * 64;   // d (512)
    int n0 = blockIdx.x * 128 + (wave & 1) * 64;    // n (4096)
    int lm = lane & 15, kq = lane >> 4;
#pragma unroll
    for (int i = 0; i < 4; ++i)
#pragma unroll
        for (int j = 0; j < 4; ++j)
#pragma unroll
            for (int r = 0; r < 4; ++r) {
                int d = m0 + i * 16 + kq * 4 + r;
                int n = n0 + j * 16 + lm;
                float h = bn2s[d] * acc[i][j][r] + bn2h[d];
                size_t gi = ((size_t)(b * 512 + d)) * 4096 + n;
                out[gi] = x[gi] + silu_f(h);
            }
}

// ------------------------------- launcher ----------------------------------

extern "C" void kernel_launch(void* const* d_in, const int* in_sizes, int n_in,
                              void* d_out, int out_size, void* d_ws, size_t ws_size,
                              hipStream_t stream)
{
    (void)in_sizes; (void)n_in; (void)out_size; (void)ws_size;
    const float* x     = (const float*)d_in[0];
    const float* cv1_w = (const float*)d_in[1];
    const float* bn1_g = (const float*)d_in[2];
    const float* bn1_b = (const float*)d_in[3];
    const float* bn1_m = (const float*)d_in[4];
    const float* bn1_v = (const float*)d_in[5];
    const float* q_w   = (const float*)d_in[6];
    const float* q_b   = (const float*)d_in[7];
    const float* k_w   = (const float*)d_in[8];
    const float* k_b   = (const float*)d_in[9];
    const float* v_w   = (const float*)d_in[10];
    const float* v_b   = (const float*)d_in[11];
    const float* e_w   = (const float*)d_in[12];
    const float* e_b   = (const float*)d_in[13];
    const float* rel_h = (const float*)d_in[14];
    const float* rel_w = (const float*)d_in[15];
    const float* cv2_w = (const float*)d_in[16];
    const float* bn2_g = (const float*)d_in[17];
    const float* bn2_b = (const float*)d_in[18];
    const float* bn2_m = (const float*)d_in[19];
    const float* bn2_v = (const float*)d_in[20];
    float* out = (float*)d_out;

    char* ws = (char*)d_ws;
    // P_grp region (128 MB) also hosts xt/x1t/v_nm/e_nm (dead before attention)
    bf16* P     = (bf16*)(ws + 0);            // 128 MB [4][4096][4096]
    bf16* xt    = (bf16*)(ws + 0);            //  32 MB overlay
    bf16* x1t   = (bf16*)(ws + 33554432);     //  16 MB overlay
    bf16* v_nm  = (bf16*)(ws + 50331648);     //  16 MB overlay
    bf16* e_nm  = (bf16*)(ws + 67108864);     //  16 MB overlay
    bf16* qk    = (bf16*)(ws + 134217728);    //  32 MB [32768][512] (q|k)
    bf16* v_cm  = (bf16*)(ws + 167772160);    //  16 MB [8][256][4096]
    bf16* rhwT  = (bf16*)(ws + 184549376);    //   8 MB [8][4096][128]
    bf16* out_t = (bf16*)(ws + 192937984);    //  16 MB [32768][256]
    bf16* w1b   = (bf16*)(ws + 209715200);    // 256 KB
    bf16* wqkve = (bf16*)(ws + 209977344);    // 512 KB
    bf16* w2b   = (bf16*)(ws + 210501632);    // 256 KB
    bf16* posT  = (bf16*)(ws + 210763776);    //  64 KB [128][256]
    float* biasq= (float*)(ws + 210829312);   //   4 KB
    float* bn1s = (float*)(ws + 210833408);
    float* bn1h = (float*)(ws + 210834432);
    float* bn2s = (float*)(ws + 210835456);
    float* bn2h = (float*)(ws + 210837504);
    float* lsum = (float*)(ws + 210839552);   // 128 KB [2][4][4096] fp32
    bf16* pacc  = (bf16*)(ws + 211288064);    //  16 MB [2][16384][256] partials

    prep_misc_kernel<<<2183, 256, 0, stream>>>(
        cv1_w, q_w, q_b, k_w, k_b, v_w, v_b, e_w, e_b, cv2_w,
        bn1_g, bn1_b, bn1_m, bn1_v, bn2_g, bn2_b, bn2_m, bn2_v,
        rel_h, rel_w,
        w1b, wqkve, w2b, posT, biasq, bn1s, bn1h, bn2s, bn2h);
    zero_lsum_kernel<<<128, 256, 0, stream>>>(lsum);
    transpose_x_kernel<<<dim3(64, 8, 8), 256, 0, stream>>>(x, xt);
    gemm1_kernel<<<dim3(2, 256), 256, 0, stream>>>(xt, w1b, bn1s, bn1h, x1t);
    gemm2_kernel<<<dim3(8, 256), 256, 0, stream>>>(x1t, wqkve, biasq, qk, v_nm, e_nm);
    gemm_rhw_kernel<<<dim3(32, 1, 8), 256, 0, stream>>>(posT, e_nm, rhwT);
    transpose_v_kernel<<<dim3(64, 4, 8), 256, 0, stream>>>(v_nm, v_cm);
    for (int g = 0; g < 2; ++g) {
        float* ls = lsum + (size_t)g * 4 * 4096;
        gemm3b_kernel<<<dim3(32, 32, 4), 256, 0, stream>>>(qk, rhwT, P, ls, g * 4);
        gemm4b_kernel<<<dim3(2, 32, 8), 256, 0, stream>>>(P, v_cm, pacc, g * 4);
        reduce4_kernel<<<2048, 256, 0, stream>>>(pacc, ls, out_t, g * 4);
    }
    gemm5_kernel<<<dim3(32, 4, 8), 256, 0, stream>>>(w2b, out_t, bn2s, bn2h, x, out);
}

// Round 4
// 665.595 us; speedup vs baseline: 1.0527x; 1.0527x over previous
//
#include <hip/hip_runtime.h>

// ---------------------------------------------------------------------------
// ExtraPositionPromptSABottleneck on MI355X (gfx950)
// B=8, DIMS=512, C=256, H=W=64, N=4096.
//
// Round 8:
//  - Counted-vmcnt pipelined GEMM core (T4): per K-step, issue next tile's
//    4 global_load_lds FIRST, then s_waitcnt vmcnt(4) (current tile ready,
//    next tile still in flight), then RAW s_barrier (no vmcnt(0) drain!),
//    compute, raw barrier.  r6 (K-halving no-op) + r7 (__syncthreads-based
//    dbuf no-op) proved every iteration ate a full exposed-latency drain --
//    __syncthreads lowers to s_waitcnt vmcnt(0) before s_barrier.
//  - Everything else held fixed from round 7 (algebra, split-K gemm4b,
//    reduce4, XCD swizzle) so the core change is cleanly attributable.
// ---------------------------------------------------------------------------

typedef __bf16 bf16;
typedef __attribute__((ext_vector_type(8))) __bf16 bf16x8;
typedef __attribute__((ext_vector_type(4))) __bf16 bf16x4;
typedef __attribute__((ext_vector_type(4))) float f32x4;

__device__ __forceinline__ float silu_f(float x) { return x / (1.f + __expf(-x)); }

__device__ __forceinline__ void zero_acc(f32x4 (&acc)[4][4])
{
#pragma unroll
    for (int i = 0; i < 4; ++i)
#pragma unroll
        for (int j = 0; j < 4; ++j)
            acc[i][j] = (f32x4){0.f, 0.f, 0.f, 0.f};
}

__device__ __forceinline__ void load_lds16(const bf16* g, bf16* l)
{
    __builtin_amdgcn_global_load_lds(
        (const __attribute__((address_space(1))) unsigned int*)g,
        (__attribute__((address_space(3))) unsigned int*)l, 16, 0, 0);
}

__device__ __forceinline__ void wg_barrier()
{
    asm volatile("" ::: "memory");
    __builtin_amdgcn_s_barrier();
    asm volatile("" ::: "memory");
}

// ---- counted-vmcnt double-buffered GEMM core: 256 thr, tile 128x128, BK=32
// A: block's 128 rows, k-contig stride lda. B: block's 128 "cols", stride ldb.
// LDS slot (row, kb) holds global (row, kb ^ ((row>>1)&3)) -- XOR swizzle.
// Per iter: issue tile t+1 loads -> s_waitcnt vmcnt(4) (tile t ready, t+1 in
// flight ACROSS the barrier) -> s_barrier -> ds_read+MFMA tile t -> s_barrier.
__device__ __forceinline__ void gemm_core_db(
    const bf16* __restrict__ A, int lda,
    const bf16* __restrict__ B, int ldb,
    int K, f32x4 (&acc)[4][4])
{
    __shared__ bf16 As[2][128 * 32];
    __shared__ bf16 Bs[2][128 * 32];
    const int tid = threadIdx.x;
    const int wave = tid >> 6;
    const int lane = tid & 63;
    const int lm = lane & 15;
    const int kq = lane >> 4;
    const int m0 = (wave >> 1) * 64;
    const int n0 = (wave & 1) * 64;
    // staging: each thread supplies 16B per round; 2 rounds per matrix.
    const int srow = tid >> 2;                              // rows 0..63, +64
    const int skoff = (((tid & 3) ^ ((tid >> 3) & 3))) * 8; // swizzled k-block
    const int krd = (kq ^ ((lm >> 1) & 3)) * 8;             // read-side offset
    zero_acc(acc);
    const bf16* ga = A + (size_t)srow * lda + skoff;
    const bf16* gb = B + (size_t)srow * ldb + skoff;
    // prologue: stage tile 0 into buffer 0
    load_lds16(ga, As[0] + tid * 8);
    load_lds16(ga + (size_t)64 * lda, As[0] + tid * 8 + 64 * 32);
    load_lds16(gb, Bs[0] + tid * 8);
    load_lds16(gb + (size_t)64 * ldb, Bs[0] + tid * 8 + 64 * 32);
    const int nt = K >> 5;
    for (int t = 0; t < nt; ++t) {
        const int cur = t & 1;
        if (t + 1 < nt) {
            // issue next tile into the other buffer (read last in iter t-1;
            // barrier2(t-1) ordered all those reads before this point)
            const bf16* na = ga + (t + 1) * 32;
            const bf16* nb = gb + (t + 1) * 32;
            bf16* dA = As[cur ^ 1] + tid * 8;
            bf16* dB = Bs[cur ^ 1] + tid * 8;
            load_lds16(na, dA);
            load_lds16(na + (size_t)64 * lda, dA + 64 * 32);
            load_lds16(nb, dB);
            load_lds16(nb + (size_t)64 * ldb, dB + 64 * 32);
            asm volatile("s_waitcnt vmcnt(4)" ::: "memory");
        } else {
            asm volatile("s_waitcnt vmcnt(0)" ::: "memory");
        }
        wg_barrier();   // raw barrier: tile t+1 loads stay in flight
        const bf16* as = As[cur];
        const bf16* bs = Bs[cur];
        bf16x8 av[4], bv[4];
#pragma unroll
        for (int tt = 0; tt < 4; ++tt)
            av[tt] = *(const bf16x8*)(as + (m0 + tt * 16 + lm) * 32 + krd);
#pragma unroll
        for (int tt = 0; tt < 4; ++tt)
            bv[tt] = *(const bf16x8*)(bs + (n0 + tt * 16 + lm) * 32 + krd);
#pragma unroll
        for (int i = 0; i < 4; ++i)
#pragma unroll
            for (int j = 0; j < 4; ++j)
                acc[i][j] = __builtin_amdgcn_mfma_f32_16x16x32_bf16(
                    av[i], bv[j], acc[i][j], 0, 0, 0);
        wg_barrier();   // all waves done reading buf[cur] before next issue
    }
}

// ------------------------------ prep kernels -------------------------------

__global__ __launch_bounds__(256) void prep_misc_kernel(
    const float* __restrict__ cv1_w,
    const float* __restrict__ qw, const float* __restrict__ qb,
    const float* __restrict__ kw, const float* __restrict__ kb,
    const float* __restrict__ vw, const float* __restrict__ vb,
    const float* __restrict__ ew, const float* __restrict__ eb,
    const float* __restrict__ cv2_w,
    const float* __restrict__ g1, const float* __restrict__ b1,
    const float* __restrict__ m1, const float* __restrict__ v1,
    const float* __restrict__ g2, const float* __restrict__ b2,
    const float* __restrict__ m2, const float* __restrict__ v2,
    const float* __restrict__ rel_h, const float* __restrict__ rel_w,
    bf16* __restrict__ w1b, bf16* __restrict__ wqkve, bf16* __restrict__ w2b,
    bf16* __restrict__ posT,
    float* __restrict__ biasq,
    float* __restrict__ bn1s, float* __restrict__ bn1h,
    float* __restrict__ bn2s, float* __restrict__ bn2h)
{
    int idx = blockIdx.x * 256 + threadIdx.x;
    if (idx < 131072) { w1b[idx] = (bf16)cv1_w[idx]; return; }
    idx -= 131072;
    if (idx < 262144) {
        int j = idx >> 8, c = idx & 255;
        int p = j >> 8, r = j & 255;
        const float* w = (p == 0) ? qw : (p == 1) ? kw : (p == 2) ? vw : ew;
        wqkve[idx] = (bf16)w[r * 256 + c];
        return;
    }
    idx -= 262144;
    if (idx < 131072) { w2b[idx] = (bf16)cv2_w[idx]; return; }
    idx -= 131072;
    if (idx < 1024) {
        int p = idx >> 8, r = idx & 255;
        const float* bb = (p == 0) ? qb : (p == 1) ? kb : (p == 2) ? vb : eb;
        biasq[idx] = bb[r];
        return;
    }
    idx -= 1024;
    if (idx < 256) {
        float s = g1[idx] * rsqrtf(v1[idx] + 1e-5f);
        bn1s[idx] = s;
        bn1h[idx] = b1[idx] - m1[idx] * s;
        return;
    }
    idx -= 256;
    if (idx < 512) {
        float s = g2[idx] * rsqrtf(v2[idx] + 1e-5f);
        bn2s[idx] = s;
        bn2h[idx] = b2[idx] - m2[idx] * s;
        return;
    }
    idx -= 512;
    if (idx < 32768) {
        // posT[r][c], r<64: rel_h[c][r]; r>=64: rel_w[c][r-64]
        int r = idx >> 8, c = idx & 255;
        posT[idx] = (bf16)((r < 64) ? rel_h[c * 64 + r] : rel_w[c * 64 + (r - 64)]);
        return;
    }
}

__global__ __launch_bounds__(256) void zero_lsum_kernel(float* __restrict__ p)
{
    p[blockIdx.x * 256 + threadIdx.x] = 0.f;
}

// xt[b*4096+n][d] = (bf16) x[b][d][n]
__global__ __launch_bounds__(256) void transpose_x_kernel(
    const float* __restrict__ x, bf16* __restrict__ xt)
{
    __shared__ float tile[64][65];
    int b = blockIdx.z;
    int n0 = blockIdx.x * 64;
    int d0 = blockIdx.y * 64;
    int tx = threadIdx.x & 63, ty = threadIdx.x >> 6;
#pragma unroll
    for (int i = 0; i < 16; ++i) {
        int d = i * 4 + ty;
        tile[d][tx] = x[((size_t)(b * 512 + d0 + d)) * 4096 + n0 + tx];
    }
    __syncthreads();
#pragma unroll
    for (int i = 0; i < 16; ++i) {
        int n = i * 4 + ty;
        xt[((size_t)(b * 4096 + n0 + n)) * 512 + d0 + tx] = (bf16)tile[tx][n];
    }
}

// v_cm[b][c][m] = v_nm[b*4096+m][c]
__global__ __launch_bounds__(256) void transpose_v_kernel(
    const bf16* __restrict__ v_nm, bf16* __restrict__ v_cm)
{
    __shared__ float tile[64][65];
    int b = blockIdx.z;
    int m0 = blockIdx.x * 64;
    int c0 = blockIdx.y * 64;
    int tx = threadIdx.x & 63, ty = threadIdx.x >> 6;
#pragma unroll
    for (int i = 0; i < 16; ++i) {
        int m = i * 4 + ty;
        tile[m][tx] = (float)v_nm[((size_t)(b * 4096 + m0 + m)) * 256 + c0 + tx];
    }
    __syncthreads();
#pragma unroll
    for (int i = 0; i < 16; ++i) {
        int c = i * 4 + ty;
        v_cm[((size_t)(b * 256 + c0 + c)) * 4096 + m0 + tx] = (bf16)tile[tx][c];
    }
}

// ------------------------------ GEMM kernels -------------------------------

// x1t[row][col] = silu(bn1( sum_d xt[row][d] * w1b[col][d] ))
__global__ __launch_bounds__(256) void gemm1_kernel(
    const bf16* __restrict__ xt, const bf16* __restrict__ w1b,
    const float* __restrict__ bn1s, const float* __restrict__ bn1h,
    bf16* __restrict__ x1t)
{
    const bf16* A = xt + (size_t)(blockIdx.y * 128) * 512;
    const bf16* Bm = w1b + (size_t)(blockIdx.x * 128) * 512;
    f32x4 acc[4][4];
    gemm_core_db(A, 512, Bm, 512, 512, acc);
    int wave = threadIdx.x >> 6;
    int lane = threadIdx.x & 63;
    int m0 = blockIdx.y * 128 + (wave >> 1) * 64;
    int n0 = blockIdx.x * 128 + (wave & 1) * 64;
    int lm = lane & 15, kq = lane >> 4;
#pragma unroll
    for (int i = 0; i < 4; ++i)
#pragma unroll
        for (int j = 0; j < 4; ++j)
#pragma unroll
            for (int r = 0; r < 4; ++r) {
                int row = m0 + i * 16 + kq * 4 + r;
                int col = n0 + j * 16 + lm;
                float h = bn1s[col] * acc[i][j][r] + bn1h[col];
                x1t[(size_t)row * 256 + col] = (bf16)silu_f(h);
            }
}

// projections: col<512 -> qk[.][col]; <768 -> v_nm[.][col-512]; else e_nm
__global__ __launch_bounds__(256) void gemm2_kernel(
    const bf16* __restrict__ x1t, const bf16* __restrict__ wqkve,
    const float* __restrict__ biasq,
    bf16* __restrict__ qk, bf16* __restrict__ v_nm, bf16* __restrict__ e_nm)
{
    const bf16* A = x1t + (size_t)(blockIdx.y * 128) * 256;
    const bf16* Bm = wqkve + (size_t)(blockIdx.x * 128) * 256;
    f32x4 acc[4][4];
    gemm_core_db(A, 256, Bm, 256, 256, acc);
    int wave = threadIdx.x >> 6;
    int lane = threadIdx.x & 63;
    int m0 = blockIdx.y * 128 + (wave >> 1) * 64;
    int n0 = blockIdx.x * 128 + (wave & 1) * 64;
    int lm = lane & 15, kq = lane >> 4;
#pragma unroll
    for (int i = 0; i < 4; ++i)
#pragma unroll
        for (int j = 0; j < 4; ++j)
#pragma unroll
            for (int r = 0; r < 4; ++r) {
                int row = m0 + i * 16 + kq * 4 + r;
                int col = n0 + j * 16 + lm;
                bf16 val = (bf16)(acc[i][j][r] + biasq[col]);
                if (col < 512)       qk[(size_t)row * 512 + col] = val;
                else if (col < 768)  v_nm[(size_t)row * 256 + (col - 512)] = val;
                else                 e_nm[(size_t)row * 256 + (col - 768)] = val;
            }
}

// rhwT[b][m][r] = sum_c posT[r][c] * e_nm[b*4096+m][c]  (r<64: RH, r>=64: RW)
__global__ __launch_bounds__(256) void gemm_rhw_kernel(
    const bf16* __restrict__ posT, const bf16* __restrict__ e_nm,
    bf16* __restrict__ rhwT)
{
    int b = blockIdx.z;
    const bf16* A = e_nm + ((size_t)b * 4096 + blockIdx.x * 128) * 256;
    f32x4 acc[4][4];
    gemm_core_db(A, 256, posT, 256, 256, acc);
    int wave = threadIdx.x >> 6;
    int lane = threadIdx.x & 63;
    int m0 = (wave >> 1) * 64, n0 = (wave & 1) * 64;
    int lm = lane & 15, kq = lane >> 4;
    bf16* rb = rhwT + ((size_t)b * 4096 + blockIdx.x * 128) * 128;
#pragma unroll
    for (int i = 0; i < 4; ++i)
#pragma unroll
        for (int j = 0; j < 4; ++j)
#pragma unroll
            for (int r = 0; r < 4; ++r)
                rb[(size_t)(m0 + i * 16 + kq * 4 + r) * 128 + n0 + j * 16 + lm] =
                    (bf16)acc[i][j][r];
}

// P[bz][n][m] = exp(q[b,n,:].k[b,m,:] + RH[h_n,m] + RW[w_n,m] - 8), bf16;
// row sums -> lsum[bz][n]
__global__ __launch_bounds__(256) void gemm3b_kernel(
    const bf16* __restrict__ qk, const bf16* __restrict__ rhwT,
    bf16* __restrict__ P, float* __restrict__ lsum, int gbase)
{
    __shared__ float rs[128];
    // XCD-aware bijective swizzle (4096 blocks, %8==0): each XCD gets a
    // contiguous 512-block chunk -> qk slice fits per-XCD 4MB L2.
    int flat = blockIdx.x + 32 * blockIdx.y + 1024 * blockIdx.z;
    flat = (flat & 7) * 512 + (flat >> 3);
    const int bx = flat & 31, by = (flat >> 5) & 31, bz = flat >> 10;
    const int b = gbase + bz;
    const int tid = threadIdx.x;
    const int wave = tid >> 6;
    const int lane = tid & 63;
    const int m0 = (wave >> 1) * 64, n0 = (wave & 1) * 64;
    const int lm = lane & 15, kq = lane >> 4;
    // ---- positional terms -> registers (L2-hot, vectorized), issued early
    // so the K-loop hides their latency.
    float rhv[4];
    bf16x4 rwv[4][4]; // [j][i]
    {
        const bf16* rbT = rhwT + ((size_t)b * 4096 + bx * 128) * 128;
        const int hidx = 2 * by + (m0 >> 6);
#pragma unroll
        for (int j = 0; j < 4; ++j) {
            const bf16* cp = rbT + (size_t)(n0 + j * 16 + lm) * 128;
            rhv[j] = (float)cp[hidx];
#pragma unroll
            for (int i = 0; i < 4; ++i)
                rwv[j][i] = *(const bf16x4*)(cp + 64 + i * 16 + kq * 4);
        }
    }
    const bf16* A = qk + ((size_t)b * 4096 + by * 128) * 512;
    const bf16* Bm = qk + ((size_t)b * 4096 + bx * 128) * 512 + 256;
    f32x4 acc[4][4];
    gemm_core_db(A, 512, Bm, 512, 256, acc);
    if (tid < 128) rs[tid] = 0.f;
    __syncthreads();
    // add positional terms, exp, per-lane row partials
    float ps[4][4];
#pragma unroll
    for (int i = 0; i < 4; ++i)
#pragma unroll
        for (int r = 0; r < 4; ++r) {
            float s = 0.f;
#pragma unroll
            for (int j = 0; j < 4; ++j) {
                float sv = acc[i][j][r] + rhv[j] + (float)rwv[j][i][r];
                float e = __expf(sv - 8.f);
                acc[i][j][r] = e;
                s += e;
            }
            ps[i][r] = s;
        }
    // butterfly over the 16-lane lm group (covers the wave's 64 cols)
#pragma unroll
    for (int msk = 1; msk < 16; msk <<= 1)
#pragma unroll
        for (int i = 0; i < 4; ++i)
#pragma unroll
            for (int r = 0; r < 4; ++r)
                ps[i][r] += __shfl_xor(ps[i][r], msk);
    if (lm == 0) {
#pragma unroll
        for (int i = 0; i < 4; ++i)
#pragma unroll
            for (int r = 0; r < 4; ++r)
                atomicAdd(&rs[m0 + i * 16 + kq * 4 + r], ps[i][r]);
    }
    // store exp(S) tile
    bf16* Pb = P + ((size_t)bz * 4096 + by * 128) * 4096 + bx * 128;
#pragma unroll
    for (int i = 0; i < 4; ++i)
#pragma unroll
        for (int j = 0; j < 4; ++j)
#pragma unroll
            for (int r = 0; r < 4; ++r)
                Pb[(size_t)(m0 + i * 16 + kq * 4 + r) * 4096 + n0 + j * 16 + lm] =
                    (bf16)acc[i][j][r];
    __syncthreads();
    if (tid < 128)
        atomicAdd(&lsum[(size_t)bz * 4096 + by * 128 + tid], rs[tid]);
}

// split-K=2 PV: pacc[kc][bz*4096+n][c] = sum_{m in chunk} P[bz][n][m]*v_cm[b][c][m]
__global__ __launch_bounds__(256) void gemm4b_kernel(
    const bf16* __restrict__ P, const bf16* __restrict__ v_cm,
    bf16* __restrict__ pacc, int gbase)
{
    int bz = blockIdx.z >> 1;
    int kc = blockIdx.z & 1;
    int b = gbase + bz;
    const bf16* A = P + ((size_t)bz * 4096 + blockIdx.y * 128) * 4096 + kc * 2048;
    const bf16* Bm = v_cm + ((size_t)b * 256 + blockIdx.x * 128) * 4096 + kc * 2048;
    f32x4 acc[4][4];
    gemm_core_db(A, 4096, Bm, 4096, 2048, acc);
    int wave = threadIdx.x >> 6;
    int lane = threadIdx.x & 63;
    int m0 = (wave >> 1) * 64, n0 = (wave & 1) * 64;
    int lm = lane & 15, kq = lane >> 4;
    bf16* ob = pacc + (((size_t)kc * 16384 + bz * 4096 + blockIdx.y * 128)) * 256
             + blockIdx.x * 128;
#pragma unroll
    for (int i = 0; i < 4; ++i)
#pragma unroll
        for (int r = 0; r < 4; ++r)
#pragma unroll
            for (int j = 0; j < 4; ++j)
                ob[(size_t)(m0 + i * 16 + kq * 4 + r) * 256 + n0 + j * 16 + lm] =
                    (bf16)acc[i][j][r];
}

// out_t[(gbase*4096)+row][c] = (pacc[0][row][c]+pacc[1][row][c]) / lsum[row]
__global__ __launch_bounds__(256) void reduce4_kernel(
    const bf16* __restrict__ pacc, const float* __restrict__ lsum,
    bf16* __restrict__ out_t, int gbase)
{
    int t = blockIdx.x * 256 + threadIdx.x;   // 524288 threads
    int row = t >> 5;                          // bz*4096+n, 0..16383
    int c0 = (t & 31) * 8;
    bf16x8 p0 = *(const bf16x8*)(pacc + (size_t)row * 256 + c0);
    bf16x8 p1 = *(const bf16x8*)(pacc + (size_t)(16384 + row) * 256 + c0);
    float inv = 1.f / lsum[row];
    bf16x8 o;
#pragma unroll
    for (int e = 0; e < 8; ++e)
        o[e] = (bf16)(((float)p0[e] + (float)p1[e]) * inv);
    *(bf16x8*)(out_t + ((size_t)gbase * 4096 + row) * 256 + c0) = o;
}

// d_out[b][d][n] = x[b][d][n] + silu(bn2( sum_c w2b[d][c]*out_t[b*4096+n][c] ))
__global__ __launch_bounds__(256) void gemm5_kernel(
    const bf16* __restrict__ w2b, const bf16* __restrict__ out_t,
    const float* __restrict__ bn2s, const float* __restrict__ bn2h,
    const float* __restrict__ x, float* __restrict__ out)
{
    int b = blockIdx.z;
    const bf16* A = w2b + (size_t)(blockIdx.y * 128) * 256;
    const bf16* Bm = out_t + ((size_t)b * 4096 + blockIdx.x * 128) * 256;
    f32x4 acc[4][4];
    gemm_core_db(A, 256, Bm, 256, 256, acc);
    int wave = threadIdx.x >> 6;
    int lane = threadIdx.x & 63;
    int m0 = blockIdx.y * 128 + (wave >> 1) * 64;   // d (512)
    int n0 = blockIdx.x * 128 + (wave & 1) * 64;    // n (4096)
    int lm = lane & 15, kq = lane >> 4;
#pragma unroll
    for (int i = 0; i < 4; ++i)
#pragma unroll
        for (int j = 0; j < 4; ++j)
#pragma unroll
            for (int r = 0; r < 4; ++r) {
                int d = m0 + i * 16 + kq * 4 + r;
                int n = n0 + j * 16 + lm;
                float h = bn2s[d] * acc[i][j][r] + bn2h[d];
                size_t gi = ((size_t)(b * 512 + d)) * 4096 + n;
                out[gi] = x[gi] + silu_f(h);
            }
}

// ------------------------------- launcher ----------------------------------

extern "C" void kernel_launch(void* const* d_in, const int* in_sizes, int n_in,
                              void* d_out, int out_size, void* d_ws, size_t ws_size,
                              hipStream_t stream)
{
    (void)in_sizes; (void)n_in; (void)out_size; (void)ws_size;
    const float* x     = (const float*)d_in[0];
    const float* cv1_w = (const float*)d_in[1];
    const float* bn1_g = (const float*)d_in[2];
    const float* bn1_b = (const float*)d_in[3];
    const float* bn1_m = (const float*)d_in[4];
    const float* bn1_v = (const float*)d_in[5];
    const float* q_w   = (const float*)d_in[6];
    const float* q_b   = (const float*)d_in[7];
    const float* k_w   = (const float*)d_in[8];
    const float* k_b   = (const float*)d_in[9];
    const float* v_w   = (const float*)d_in[10];
    const float* v_b   = (const float*)d_in[11];
    const float* e_w   = (const float*)d_in[12];
    const float* e_b   = (const float*)d_in[13];
    const float* rel_h = (const float*)d_in[14];
    const float* rel_w = (const float*)d_in[15];
    const float* cv2_w = (const float*)d_in[16];
    const float* bn2_g = (const float*)d_in[17];
    const float* bn2_b = (const float*)d_in[18];
    const float* bn2_m = (const float*)d_in[19];
    const float* bn2_v = (const float*)d_in[20];
    float* out = (float*)d_out;

    char* ws = (char*)d_ws;
    // P_grp region (128 MB) also hosts xt/x1t/v_nm/e_nm (dead before attention)
    bf16* P     = (bf16*)(ws + 0);            // 128 MB [4][4096][4096]
    bf16* xt    = (bf16*)(ws + 0);            //  32 MB overlay
    bf16* x1t   = (bf16*)(ws + 33554432);     //  16 MB overlay
    bf16* v_nm  = (bf16*)(ws + 50331648);     //  16 MB overlay
    bf16* e_nm  = (bf16*)(ws + 67108864);     //  16 MB overlay
    bf16* qk    = (bf16*)(ws + 134217728);    //  32 MB [32768][512] (q|k)
    bf16* v_cm  = (bf16*)(ws + 167772160);    //  16 MB [8][256][4096]
    bf16* rhwT  = (bf16*)(ws + 184549376);    //   8 MB [8][4096][128]
    bf16* out_t = (bf16*)(ws + 192937984);    //  16 MB [32768][256]
    bf16* w1b   = (bf16*)(ws + 209715200);    // 256 KB
    bf16* wqkve = (bf16*)(ws + 209977344);    // 512 KB
    bf16* w2b   = (bf16*)(ws + 210501632);    // 256 KB
    bf16* posT  = (bf16*)(ws + 210763776);    //  64 KB [128][256]
    float* biasq= (float*)(ws + 210829312);   //   4 KB
    float* bn1s = (float*)(ws + 210833408);
    float* bn1h = (float*)(ws + 210834432);
    float* bn2s = (float*)(ws + 210835456);
    float* bn2h = (float*)(ws + 210837504);
    float* lsum = (float*)(ws + 210839552);   // 128 KB [2][4][4096] fp32
    bf16* pacc  = (bf16*)(ws + 211288064);    //  16 MB [2][16384][256] partials

    prep_misc_kernel<<<2183, 256, 0, stream>>>(
        cv1_w, q_w, q_b, k_w, k_b, v_w, v_b, e_w, e_b, cv2_w,
        bn1_g, bn1_b, bn1_m, bn1_v, bn2_g, bn2_b, bn2_m, bn2_v,
        rel_h, rel_w,
        w1b, wqkve, w2b, posT, biasq, bn1s, bn1h, bn2s, bn2h);
    zero_lsum_kernel<<<128, 256, 0, stream>>>(lsum);
    transpose_x_kernel<<<dim3(64, 8, 8), 256, 0, stream>>>(x, xt);
    gemm1_kernel<<<dim3(2, 256), 256, 0, stream>>>(xt, w1b, bn1s, bn1h, x1t);
    gemm2_kernel<<<dim3(8, 256), 256, 0, stream>>>(x1t, wqkve, biasq, qk, v_nm, e_nm);
    gemm_rhw_kernel<<<dim3(32, 1, 8), 256, 0, stream>>>(posT, e_nm, rhwT);
    transpose_v_kernel<<<dim3(64, 4, 8), 256, 0, stream>>>(v_nm, v_cm);
    for (int g = 0; g < 2; ++g) {
        float* ls = lsum + (size_t)g * 4 * 4096;
        gemm3b_kernel<<<dim3(32, 32, 4), 256, 0, stream>>>(qk, rhwT, P, ls, g * 4);
        gemm4b_kernel<<<dim3(2, 32, 8), 256, 0, stream>>>(P, v_cm, pacc, g * 4);
        reduce4_kernel<<<2048, 256, 0, stream>>>(pacc, ls, out_t, g * 4);
    }
    gemm5_kernel<<<dim3(32, 4, 8), 256, 0, stream>>>(w2b, out_t, bn2s, bn2h, x, out);
}

// Round 5
// 612.265 us; speedup vs baseline: 1.1444x; 1.0871x over previous
//
#include <hip/hip_runtime.h>

// ---------------------------------------------------------------------------
// ExtraPositionPromptSABottleneck on MI355X (gfx950)
// B=8, DIMS=512, C=256, H=W=64, N=4096.
//
// Round 9:
//  - gemm3b rebuilt on a 256x256 tile, BK=64, 512 threads / 8 waves
//    (2m x 4n wave grid, 128x64 per wave, acc[8][4]).  r6/r7/r8 proved the
//    128^2 tile is latency-bound at a 1:8 compute:latency ratio per K-step
//    (K-halving, dbuf, counted-vmcnt all ~no-ops).  256^2 quadruples MFMA
//    per staged byte: 64 MFMA/wave/iter vs 16.  Counted vmcnt(8) prefetch,
//    XOR-swizzled LDS (3-bit, 8 chunks of 16B per 64-elem row).
//  - pos-term register loads moved to the epilogue (frees ~36 VGPR in the
//    main loop; 8-wave overlap hides their latency there).
//  - All other kernels unchanged from round 8.
// ---------------------------------------------------------------------------

typedef __bf16 bf16;
typedef __attribute__((ext_vector_type(8))) __bf16 bf16x8;
typedef __attribute__((ext_vector_type(4))) __bf16 bf16x4;
typedef __attribute__((ext_vector_type(2))) __bf16 bf16x2;
typedef __attribute__((ext_vector_type(4))) float f32x4;

__device__ __forceinline__ float silu_f(float x) { return x / (1.f + __expf(-x)); }

__device__ __forceinline__ void zero_acc(f32x4 (&acc)[4][4])
{
#pragma unroll
    for (int i = 0; i < 4; ++i)
#pragma unroll
        for (int j = 0; j < 4; ++j)
            acc[i][j] = (f32x4){0.f, 0.f, 0.f, 0.f};
}

__device__ __forceinline__ void load_lds16(const bf16* g, bf16* l)
{
    __builtin_amdgcn_global_load_lds(
        (const __attribute__((address_space(1))) unsigned int*)g,
        (__attribute__((address_space(3))) unsigned int*)l, 16, 0, 0);
}

__device__ __forceinline__ void wg_barrier()
{
    asm volatile("" ::: "memory");
    __builtin_amdgcn_s_barrier();
    asm volatile("" ::: "memory");
}

// ---- counted-vmcnt double-buffered GEMM core: 256 thr, tile 128x128, BK=32
// (used by gemm1/2/5, rhw, gemm4b -- unchanged from round 8)
__device__ __forceinline__ void gemm_core_db(
    const bf16* __restrict__ A, int lda,
    const bf16* __restrict__ B, int ldb,
    int K, f32x4 (&acc)[4][4])
{
    __shared__ bf16 As[2][128 * 32];
    __shared__ bf16 Bs[2][128 * 32];
    const int tid = threadIdx.x;
    const int wave = tid >> 6;
    const int lane = tid & 63;
    const int lm = lane & 15;
    const int kq = lane >> 4;
    const int m0 = (wave >> 1) * 64;
    const int n0 = (wave & 1) * 64;
    const int srow = tid >> 2;
    const int skoff = (((tid & 3) ^ ((tid >> 3) & 3))) * 8;
    const int krd = (kq ^ ((lm >> 1) & 3)) * 8;
    zero_acc(acc);
    const bf16* ga = A + (size_t)srow * lda + skoff;
    const bf16* gb = B + (size_t)srow * ldb + skoff;
    load_lds16(ga, As[0] + tid * 8);
    load_lds16(ga + (size_t)64 * lda, As[0] + tid * 8 + 64 * 32);
    load_lds16(gb, Bs[0] + tid * 8);
    load_lds16(gb + (size_t)64 * ldb, Bs[0] + tid * 8 + 64 * 32);
    const int nt = K >> 5;
    for (int t = 0; t < nt; ++t) {
        const int cur = t & 1;
        if (t + 1 < nt) {
            const bf16* na = ga + (t + 1) * 32;
            const bf16* nb = gb + (t + 1) * 32;
            bf16* dA = As[cur ^ 1] + tid * 8;
            bf16* dB = Bs[cur ^ 1] + tid * 8;
            load_lds16(na, dA);
            load_lds16(na + (size_t)64 * lda, dA + 64 * 32);
            load_lds16(nb, dB);
            load_lds16(nb + (size_t)64 * ldb, dB + 64 * 32);
            asm volatile("s_waitcnt vmcnt(4)" ::: "memory");
        } else {
            asm volatile("s_waitcnt vmcnt(0)" ::: "memory");
        }
        wg_barrier();
        const bf16* as = As[cur];
        const bf16* bs = Bs[cur];
        bf16x8 av[4], bv[4];
#pragma unroll
        for (int tt = 0; tt < 4; ++tt)
            av[tt] = *(const bf16x8*)(as + (m0 + tt * 16 + lm) * 32 + krd);
#pragma unroll
        for (int tt = 0; tt < 4; ++tt)
            bv[tt] = *(const bf16x8*)(bs + (n0 + tt * 16 + lm) * 32 + krd);
#pragma unroll
        for (int i = 0; i < 4; ++i)
#pragma unroll
            for (int j = 0; j < 4; ++j)
                acc[i][j] = __builtin_amdgcn_mfma_f32_16x16x32_bf16(
                    av[i], bv[j], acc[i][j], 0, 0, 0);
        wg_barrier();
    }
}

// ------------------------------ prep kernels -------------------------------

__global__ __launch_bounds__(256) void prep_misc_kernel(
    const float* __restrict__ cv1_w,
    const float* __restrict__ qw, const float* __restrict__ qb,
    const float* __restrict__ kw, const float* __restrict__ kb,
    const float* __restrict__ vw, const float* __restrict__ vb,
    const float* __restrict__ ew, const float* __restrict__ eb,
    const float* __restrict__ cv2_w,
    const float* __restrict__ g1, const float* __restrict__ b1,
    const float* __restrict__ m1, const float* __restrict__ v1,
    const float* __restrict__ g2, const float* __restrict__ b2,
    const float* __restrict__ m2, const float* __restrict__ v2,
    const float* __restrict__ rel_h, const float* __restrict__ rel_w,
    bf16* __restrict__ w1b, bf16* __restrict__ wqkve, bf16* __restrict__ w2b,
    bf16* __restrict__ posT,
    float* __restrict__ biasq,
    float* __restrict__ bn1s, float* __restrict__ bn1h,
    float* __restrict__ bn2s, float* __restrict__ bn2h)
{
    int idx = blockIdx.x * 256 + threadIdx.x;
    if (idx < 131072) { w1b[idx] = (bf16)cv1_w[idx]; return; }
    idx -= 131072;
    if (idx < 262144) {
        int j = idx >> 8, c = idx & 255;
        int p = j >> 8, r = j & 255;
        const float* w = (p == 0) ? qw : (p == 1) ? kw : (p == 2) ? vw : ew;
        wqkve[idx] = (bf16)w[r * 256 + c];
        return;
    }
    idx -= 262144;
    if (idx < 131072) { w2b[idx] = (bf16)cv2_w[idx]; return; }
    idx -= 131072;
    if (idx < 1024) {
        int p = idx >> 8, r = idx & 255;
        const float* bb = (p == 0) ? qb : (p == 1) ? kb : (p == 2) ? vb : eb;
        biasq[idx] = bb[r];
        return;
    }
    idx -= 1024;
    if (idx < 256) {
        float s = g1[idx] * rsqrtf(v1[idx] + 1e-5f);
        bn1s[idx] = s;
        bn1h[idx] = b1[idx] - m1[idx] * s;
        return;
    }
    idx -= 256;
    if (idx < 512) {
        float s = g2[idx] * rsqrtf(v2[idx] + 1e-5f);
        bn2s[idx] = s;
        bn2h[idx] = b2[idx] - m2[idx] * s;
        return;
    }
    idx -= 512;
    if (idx < 32768) {
        int r = idx >> 8, c = idx & 255;
        posT[idx] = (bf16)((r < 64) ? rel_h[c * 64 + r] : rel_w[c * 64 + (r - 64)]);
        return;
    }
}

__global__ __launch_bounds__(256) void zero_lsum_kernel(float* __restrict__ p)
{
    p[blockIdx.x * 256 + threadIdx.x] = 0.f;
}

// xt[b*4096+n][d] = (bf16) x[b][d][n]
__global__ __launch_bounds__(256) void transpose_x_kernel(
    const float* __restrict__ x, bf16* __restrict__ xt)
{
    __shared__ float tile[64][65];
    int b = blockIdx.z;
    int n0 = blockIdx.x * 64;
    int d0 = blockIdx.y * 64;
    int tx = threadIdx.x & 63, ty = threadIdx.x >> 6;
#pragma unroll
    for (int i = 0; i < 16; ++i) {
        int d = i * 4 + ty;
        tile[d][tx] = x[((size_t)(b * 512 + d0 + d)) * 4096 + n0 + tx];
    }
    __syncthreads();
#pragma unroll
    for (int i = 0; i < 16; ++i) {
        int n = i * 4 + ty;
        xt[((size_t)(b * 4096 + n0 + n)) * 512 + d0 + tx] = (bf16)tile[tx][n];
    }
}

// v_cm[b][c][m] = v_nm[b*4096+m][c]
__global__ __launch_bounds__(256) void transpose_v_kernel(
    const bf16* __restrict__ v_nm, bf16* __restrict__ v_cm)
{
    __shared__ float tile[64][65];
    int b = blockIdx.z;
    int m0 = blockIdx.x * 64;
    int c0 = blockIdx.y * 64;
    int tx = threadIdx.x & 63, ty = threadIdx.x >> 6;
#pragma unroll
    for (int i = 0; i < 16; ++i) {
        int m = i * 4 + ty;
        tile[m][tx] = (float)v_nm[((size_t)(b * 4096 + m0 + m)) * 256 + c0 + tx];
    }
    __syncthreads();
#pragma unroll
    for (int i = 0; i < 16; ++i) {
        int c = i * 4 + ty;
        v_cm[((size_t)(b * 256 + c0 + c)) * 4096 + m0 + tx] = (bf16)tile[tx][c];
    }
}

// ------------------------------ GEMM kernels -------------------------------

__global__ __launch_bounds__(256) void gemm1_kernel(
    const bf16* __restrict__ xt, const bf16* __restrict__ w1b,
    const float* __restrict__ bn1s, const float* __restrict__ bn1h,
    bf16* __restrict__ x1t)
{
    const bf16* A = xt + (size_t)(blockIdx.y * 128) * 512;
    const bf16* Bm = w1b + (size_t)(blockIdx.x * 128) * 512;
    f32x4 acc[4][4];
    gemm_core_db(A, 512, Bm, 512, 512, acc);
    int wave = threadIdx.x >> 6;
    int lane = threadIdx.x & 63;
    int m0 = blockIdx.y * 128 + (wave >> 1) * 64;
    int n0 = blockIdx.x * 128 + (wave & 1) * 64;
    int lm = lane & 15, kq = lane >> 4;
#pragma unroll
    for (int i = 0; i < 4; ++i)
#pragma unroll
        for (int j = 0; j < 4; ++j)
#pragma unroll
            for (int r = 0; r < 4; ++r) {
                int row = m0 + i * 16 + kq * 4 + r;
                int col = n0 + j * 16 + lm;
                float h = bn1s[col] * acc[i][j][r] + bn1h[col];
                x1t[(size_t)row * 256 + col] = (bf16)silu_f(h);
            }
}

__global__ __launch_bounds__(256) void gemm2_kernel(
    const bf16* __restrict__ x1t, const bf16* __restrict__ wqkve,
    const float* __restrict__ biasq,
    bf16* __restrict__ qk, bf16* __restrict__ v_nm, bf16* __restrict__ e_nm)
{
    const bf16* A = x1t + (size_t)(blockIdx.y * 128) * 256;
    const bf16* Bm = wqkve + (size_t)(blockIdx.x * 128) * 256;
    f32x4 acc[4][4];
    gemm_core_db(A, 256, Bm, 256, 256, acc);
    int wave = threadIdx.x >> 6;
    int lane = threadIdx.x & 63;
    int m0 = blockIdx.y * 128 + (wave >> 1) * 64;
    int n0 = blockIdx.x * 128 + (wave & 1) * 64;
    int lm = lane & 15, kq = lane >> 4;
#pragma unroll
    for (int i = 0; i < 4; ++i)
#pragma unroll
        for (int j = 0; j < 4; ++j)
#pragma unroll
            for (int r = 0; r < 4; ++r) {
                int row = m0 + i * 16 + kq * 4 + r;
                int col = n0 + j * 16 + lm;
                bf16 val = (bf16)(acc[i][j][r] + biasq[col]);
                if (col < 512)       qk[(size_t)row * 512 + col] = val;
                else if (col < 768)  v_nm[(size_t)row * 256 + (col - 512)] = val;
                else                 e_nm[(size_t)row * 256 + (col - 768)] = val;
            }
}

// rhwT[b][m][r] = sum_c posT[r][c] * e_nm[b*4096+m][c]  (r<64: RH, r>=64: RW)
__global__ __launch_bounds__(256) void gemm_rhw_kernel(
    const bf16* __restrict__ posT, const bf16* __restrict__ e_nm,
    bf16* __restrict__ rhwT)
{
    int b = blockIdx.z;
    const bf16* A = e_nm + ((size_t)b * 4096 + blockIdx.x * 128) * 256;
    f32x4 acc[4][4];
    gemm_core_db(A, 256, posT, 256, 256, acc);
    int wave = threadIdx.x >> 6;
    int lane = threadIdx.x & 63;
    int m0 = (wave >> 1) * 64, n0 = (wave & 1) * 64;
    int lm = lane & 15, kq = lane >> 4;
    bf16* rb = rhwT + ((size_t)b * 4096 + blockIdx.x * 128) * 128;
#pragma unroll
    for (int i = 0; i < 4; ++i)
#pragma unroll
        for (int j = 0; j < 4; ++j)
#pragma unroll
            for (int r = 0; r < 4; ++r)
                rb[(size_t)(m0 + i * 16 + kq * 4 + r) * 128 + n0 + j * 16 + lm] =
                    (bf16)acc[i][j][r];
}

// P[bz][n][m] = exp(q.k + RH + RW - 8), bf16; row sums -> lsum[bz][n]
// 256x256 tile, BK=64, 512 threads, 8 waves (2m x 4n), acc[8][4].
__global__ __launch_bounds__(512, 1) void gemm3b_kernel(
    const bf16* __restrict__ qk, const bf16* __restrict__ rhwT,
    bf16* __restrict__ P, float* __restrict__ lsum, int gbase)
{
    __shared__ bf16 As[2][16384];   // [256][64] per buffer
    __shared__ bf16 Bs[2][16384];
    __shared__ float rs[256];
    // XCD-aware bijective swizzle (1024 blocks % 8 == 0)
    int flat = blockIdx.x + 16 * blockIdx.y + 256 * blockIdx.z;
    flat = (flat & 7) * 128 + (flat >> 3);
    const int bx = flat & 15, by = (flat >> 4) & 15, bz = flat >> 8;
    const int b = gbase + bz;
    const int tid = threadIdx.x;
    const int wid = tid >> 6;
    const int lane = tid & 63;
    const int wm = wid >> 2, wn = wid & 3;      // wave grid 2 x 4
    const int lm = lane & 15, kq = lane >> 4;
    const bf16* A = qk + ((size_t)b * 4096 + by * 256) * 512;        // q rows
    const bf16* Bm = qk + ((size_t)b * 4096 + bx * 256) * 512 + 256; // k rows
    // staging: 512 thr x 16B = 64 rows/round; 4 rounds per matrix.
    // LDS slot (row, chunk) holds global chunk ^ (row&7)  [3-bit XOR swizzle]
    const int srow = tid >> 3;
    const int skoff = (((tid & 7) ^ (srow & 7))) * 8;
    const bf16* ga = A + (size_t)srow * 512 + skoff;
    const bf16* gb = Bm + (size_t)srow * 512 + skoff;
#pragma unroll
    for (int r = 0; r < 4; ++r)
        load_lds16(ga + (size_t)(64 * r) * 512, As[0] + tid * 8 + r * 4096);
#pragma unroll
    for (int r = 0; r < 4; ++r)
        load_lds16(gb + (size_t)(64 * r) * 512, Bs[0] + tid * 8 + r * 4096);
    f32x4 acc[8][4];
#pragma unroll
    for (int i = 0; i < 8; ++i)
#pragma unroll
        for (int j = 0; j < 4; ++j)
            acc[i][j] = (f32x4){0.f, 0.f, 0.f, 0.f};
    for (int t = 0; t < 4; ++t) {            // K = 256, BK = 64
        const int cur = t & 1;
        if (t < 3) {
            const bf16* na = ga + (t + 1) * 64;
            const bf16* nb = gb + (t + 1) * 64;
#pragma unroll
            for (int r = 0; r < 4; ++r)
                load_lds16(na + (size_t)(64 * r) * 512,
                           As[cur ^ 1] + tid * 8 + r * 4096);
#pragma unroll
            for (int r = 0; r < 4; ++r)
                load_lds16(nb + (size_t)(64 * r) * 512,
                           Bs[cur ^ 1] + tid * 8 + r * 4096);
            asm volatile("s_waitcnt vmcnt(8)" ::: "memory");
        } else {
            asm volatile("s_waitcnt vmcnt(0)" ::: "memory");
        }
        wg_barrier();
        const bf16* as = As[cur];
        const bf16* bs = Bs[cur];
#pragma unroll
        for (int ks = 0; ks < 2; ++ks) {
            bf16x8 av[8], bv[4];
#pragma unroll
            for (int i = 0; i < 8; ++i) {
                int lr = wm * 128 + i * 16 + lm;
                av[i] = *(const bf16x8*)(as + lr * 64 +
                                         (((ks << 2) | kq) ^ (lr & 7)) * 8);
            }
#pragma unroll
            for (int j = 0; j < 4; ++j) {
                int lr = wn * 64 + j * 16 + lm;
                bv[j] = *(const bf16x8*)(bs + lr * 64 +
                                         (((ks << 2) | kq) ^ (lr & 7)) * 8);
            }
#pragma unroll
            for (int i = 0; i < 8; ++i)
#pragma unroll
                for (int j = 0; j < 4; ++j)
                    acc[i][j] = __builtin_amdgcn_mfma_f32_16x16x32_bf16(
                        av[i], bv[j], acc[i][j], 0, 0, 0);
        }
        wg_barrier();
    }
    // ---- positional terms (loaded now: frees VGPRs in the main loop;
    //      8-wave overlap hides the latency here)
    bf16x2 rhv2[4];
    bf16x4 rwv[4][4];
    {
        const bf16* rbT = rhwT + ((size_t)b * 4096 + bx * 256) * 128;
#pragma unroll
        for (int j = 0; j < 4; ++j) {
            const bf16* cp = rbT + (size_t)(wn * 64 + j * 16 + lm) * 128;
            rhv2[j] = *(const bf16x2*)(cp + by * 4 + wm * 2);
#pragma unroll
            for (int ii = 0; ii < 4; ++ii)
                rwv[j][ii] = *(const bf16x4*)(cp + 64 + ii * 16 + kq * 4);
        }
    }
    if (tid < 256) rs[tid] = 0.f;
    __syncthreads();
    // exp + per-lane row partials
    float ps[8][4];
#pragma unroll
    for (int i = 0; i < 8; ++i)
#pragma unroll
        for (int r = 0; r < 4; ++r) {
            float s = 0.f;
#pragma unroll
            for (int j = 0; j < 4; ++j) {
                float sv = acc[i][j][r] + (float)rhv2[j][i >> 2]
                                        + (float)rwv[j][i & 3][r];
                float e = __expf(sv - 8.f);
                acc[i][j][r] = e;
                s += e;
            }
            ps[i][r] = s;
        }
#pragma unroll
    for (int msk = 1; msk < 16; msk <<= 1)
#pragma unroll
        for (int i = 0; i < 8; ++i)
#pragma unroll
            for (int r = 0; r < 4; ++r)
                ps[i][r] += __shfl_xor(ps[i][r], msk);
    if (lm == 0) {
#pragma unroll
        for (int i = 0; i < 8; ++i)
#pragma unroll
            for (int r = 0; r < 4; ++r)
                atomicAdd(&rs[wm * 128 + i * 16 + kq * 4 + r], ps[i][r]);
    }
    // store exp(S) tile
    bf16* Pb = P + ((size_t)bz * 4096 + by * 256) * 4096 + bx * 256;
#pragma unroll
    for (int i = 0; i < 8; ++i)
#pragma unroll
        for (int j = 0; j < 4; ++j)
#pragma unroll
            for (int r = 0; r < 4; ++r)
                Pb[(size_t)(wm * 128 + i * 16 + kq * 4 + r) * 4096
                   + wn * 64 + j * 16 + lm] = (bf16)acc[i][j][r];
    __syncthreads();
    if (tid < 256)
        atomicAdd(&lsum[(size_t)bz * 4096 + by * 256 + tid], rs[tid]);
}

// split-K=2 PV: pacc[kc][bz*4096+n][c] = sum_{m in chunk} P[bz][n][m]*v_cm[b][c][m]
__global__ __launch_bounds__(256) void gemm4b_kernel(
    const bf16* __restrict__ P, const bf16* __restrict__ v_cm,
    bf16* __restrict__ pacc, int gbase)
{
    int bz = blockIdx.z >> 1;
    int kc = blockIdx.z & 1;
    int b = gbase + bz;
    const bf16* A = P + ((size_t)bz * 4096 + blockIdx.y * 128) * 4096 + kc * 2048;
    const bf16* Bm = v_cm + ((size_t)b * 256 + blockIdx.x * 128) * 4096 + kc * 2048;
    f32x4 acc[4][4];
    gemm_core_db(A, 4096, Bm, 4096, 2048, acc);
    int wave = threadIdx.x >> 6;
    int lane = threadIdx.x & 63;
    int m0 = (wave >> 1) * 64, n0 = (wave & 1) * 64;
    int lm = lane & 15, kq = lane >> 4;
    bf16* ob = pacc + (((size_t)kc * 16384 + bz * 4096 + blockIdx.y * 128)) * 256
             + blockIdx.x * 128;
#pragma unroll
    for (int i = 0; i < 4; ++i)
#pragma unroll
        for (int r = 0; r < 4; ++r)
#pragma unroll
            for (int j = 0; j < 4; ++j)
                ob[(size_t)(m0 + i * 16 + kq * 4 + r) * 256 + n0 + j * 16 + lm] =
                    (bf16)acc[i][j][r];
}

// out_t[(gbase*4096)+row][c] = (pacc[0][row][c]+pacc[1][row][c]) / lsum[row]
__global__ __launch_bounds__(256) void reduce4_kernel(
    const bf16* __restrict__ pacc, const float* __restrict__ lsum,
    bf16* __restrict__ out_t, int gbase)
{
    int t = blockIdx.x * 256 + threadIdx.x;
    int row = t >> 5;
    int c0 = (t & 31) * 8;
    bf16x8 p0 = *(const bf16x8*)(pacc + (size_t)row * 256 + c0);
    bf16x8 p1 = *(const bf16x8*)(pacc + (size_t)(16384 + row) * 256 + c0);
    float inv = 1.f / lsum[row];
    bf16x8 o;
#pragma unroll
    for (int e = 0; e < 8; ++e)
        o[e] = (bf16)(((float)p0[e] + (float)p1[e]) * inv);
    *(bf16x8*)(out_t + ((size_t)gbase * 4096 + row) * 256 + c0) = o;
}

// d_out[b][d][n] = x[b][d][n] + silu(bn2( sum_c w2b[d][c]*out_t[b*4096+n][c] ))
__global__ __launch_bounds__(256) void gemm5_kernel(
    const bf16* __restrict__ w2b, const bf16* __restrict__ out_t,
    const float* __restrict__ bn2s, const float* __restrict__ bn2h,
    const float* __restrict__ x, float* __restrict__ out)
{
    int b = blockIdx.z;
    const bf16* A = w2b + (size_t)(blockIdx.y * 128) * 256;
    const bf16* Bm = out_t + ((size_t)b * 4096 + blockIdx.x * 128) * 256;
    f32x4 acc[4][4];
    gemm_core_db(A, 256, Bm, 256, 256, acc);
    int wave = threadIdx.x >> 6;
    int lane = threadIdx.x & 63;
    int m0 = blockIdx.y * 128 + (wave >> 1) * 64;
    int n0 = blockIdx.x * 128 + (wave & 1) * 64;
    int lm = lane & 15, kq = lane >> 4;
#pragma unroll
    for (int i = 0; i < 4; ++i)
#pragma unroll
        for (int j = 0; j < 4; ++j)
#pragma unroll
            for (int r = 0; r < 4; ++r) {
                int d = m0 + i * 16 + kq * 4 + r;
                int n = n0 + j * 16 + lm;
                float h = bn2s[d] * acc[i][j][r] + bn2h[d];
                size_t gi = ((size_t)(b * 512 + d)) * 4096 + n;
                out[gi] = x[gi] + silu_f(h);
            }
}

// ------------------------------- launcher ----------------------------------

extern "C" void kernel_launch(void* const* d_in, const int* in_sizes, int n_in,
                              void* d_out, int out_size, void* d_ws, size_t ws_size,
                              hipStream_t stream)
{
    (void)in_sizes; (void)n_in; (void)out_size; (void)ws_size;
    const float* x     = (const float*)d_in[0];
    const float* cv1_w = (const float*)d_in[1];
    const float* bn1_g = (const float*)d_in[2];
    const float* bn1_b = (const float*)d_in[3];
    const float* bn1_m = (const float*)d_in[4];
    const float* bn1_v = (const float*)d_in[5];
    const float* q_w   = (const float*)d_in[6];
    const float* q_b   = (const float*)d_in[7];
    const float* k_w   = (const float*)d_in[8];
    const float* k_b   = (const float*)d_in[9];
    const float* v_w   = (const float*)d_in[10];
    const float* v_b   = (const float*)d_in[11];
    const float* e_w   = (const float*)d_in[12];
    const float* e_b   = (const float*)d_in[13];
    const float* rel_h = (const float*)d_in[14];
    const float* rel_w = (const float*)d_in[15];
    const float* cv2_w = (const float*)d_in[16];
    const float* bn2_g = (const float*)d_in[17];
    const float* bn2_b = (const float*)d_in[18];
    const float* bn2_m = (const float*)d_in[19];
    const float* bn2_v = (const float*)d_in[20];
    float* out = (float*)d_out;

    char* ws = (char*)d_ws;
    bf16* P     = (bf16*)(ws + 0);            // 128 MB [4][4096][4096]
    bf16* xt    = (bf16*)(ws + 0);            //  32 MB overlay
    bf16* x1t   = (bf16*)(ws + 33554432);     //  16 MB overlay
    bf16* v_nm  = (bf16*)(ws + 50331648);     //  16 MB overlay
    bf16* e_nm  = (bf16*)(ws + 67108864);     //  16 MB overlay
    bf16* qk    = (bf16*)(ws + 134217728);    //  32 MB [32768][512] (q|k)
    bf16* v_cm  = (bf16*)(ws + 167772160);    //  16 MB [8][256][4096]
    bf16* rhwT  = (bf16*)(ws + 184549376);    //   8 MB [8][4096][128]
    bf16* out_t = (bf16*)(ws + 192937984);    //  16 MB [32768][256]
    bf16* w1b   = (bf16*)(ws + 209715200);    // 256 KB
    bf16* wqkve = (bf16*)(ws + 209977344);    // 512 KB
    bf16* w2b   = (bf16*)(ws + 210501632);    // 256 KB
    bf16* posT  = (bf16*)(ws + 210763776);    //  64 KB [128][256]
    float* biasq= (float*)(ws + 210829312);   //   4 KB
    float* bn1s = (float*)(ws + 210833408);
    float* bn1h = (float*)(ws + 210834432);
    float* bn2s = (float*)(ws + 210835456);
    float* bn2h = (float*)(ws + 210837504);
    float* lsum = (float*)(ws + 210839552);   // 128 KB [2][4][4096] fp32
    bf16* pacc  = (bf16*)(ws + 211288064);    //  16 MB [2][16384][256] partials

    prep_misc_kernel<<<2183, 256, 0, stream>>>(
        cv1_w, q_w, q_b, k_w, k_b, v_w, v_b, e_w, e_b, cv2_w,
        bn1_g, bn1_b, bn1_m, bn1_v, bn2_g, bn2_b, bn2_m, bn2_v,
        rel_h, rel_w,
        w1b, wqkve, w2b, posT, biasq, bn1s, bn1h, bn2s, bn2h);
    zero_lsum_kernel<<<128, 256, 0, stream>>>(lsum);
    transpose_x_kernel<<<dim3(64, 8, 8), 256, 0, stream>>>(x, xt);
    gemm1_kernel<<<dim3(2, 256), 256, 0, stream>>>(xt, w1b, bn1s, bn1h, x1t);
    gemm2_kernel<<<dim3(8, 256), 256, 0, stream>>>(x1t, wqkve, biasq, qk, v_nm, e_nm);
    gemm_rhw_kernel<<<dim3(32, 1, 8), 256, 0, stream>>>(posT, e_nm, rhwT);
    transpose_v_kernel<<<dim3(64, 4, 8), 256, 0, stream>>>(v_nm, v_cm);
    for (int g = 0; g < 2; ++g) {
        float* ls = lsum + (size_t)g * 4 * 4096;
        gemm3b_kernel<<<dim3(16, 16, 4), 512, 0, stream>>>(qk, rhwT, P, ls, g * 4);
        gemm4b_kernel<<<dim3(2, 32, 8), 256, 0, stream>>>(P, v_cm, pacc, g * 4);
        reduce4_kernel<<<2048, 256, 0, stream>>>(pacc, ls, out_t, g * 4);
    }
    gemm5_kernel<<<dim3(32, 4, 8), 256, 0, stream>>>(w2b, out_t, bn2s, bn2h, x, out);
}

// Round 6
// 535.431 us; speedup vs baseline: 1.3086x; 1.1435x over previous
//
#include <hip/hip_runtime.h>

// ---------------------------------------------------------------------------
// ExtraPositionPromptSABottleneck on MI355X (gfx950)
// B=8, DIMS=512, C=256, H=W=64, N=4096.
//
// Round 10:
//  - Shared 256x256/BK=64/8-wave GEMM core (gemm_core_256, generic strides),
//    proven in round 9 (gemm3b 128->95us, FETCH 95->54MB).  Now also drives:
//    * gemm4b: 256 cols = all of C, split-K=4 -> 256 blocks, 4096 block-iters
//      (was 32768 of the latency-bound 128^2 core = ~240us total).  Partials
//      pacc[4] (32MB bf16) live in d_out (dead until gemm5 writes it).
//    * gemm2: grid 4x128, aligned col-split per bx.
//    * gemm5: grid 16x2x8 (floor is its 272MB x/out traffic).
//  - gemm1/rhw stay on the 128^2 core (small, half-GPU at 256^2).
// ---------------------------------------------------------------------------

typedef __bf16 bf16;
typedef __attribute__((ext_vector_type(8))) __bf16 bf16x8;
typedef __attribute__((ext_vector_type(4))) __bf16 bf16x4;
typedef __attribute__((ext_vector_type(2))) __bf16 bf16x2;
typedef __attribute__((ext_vector_type(4))) float f32x4;

__device__ __forceinline__ float silu_f(float x) { return x / (1.f + __expf(-x)); }

__device__ __forceinline__ void zero_acc(f32x4 (&acc)[4][4])
{
#pragma unroll
    for (int i = 0; i < 4; ++i)
#pragma unroll
        for (int j = 0; j < 4; ++j)
            acc[i][j] = (f32x4){0.f, 0.f, 0.f, 0.f};
}

__device__ __forceinline__ void load_lds16(const bf16* g, bf16* l)
{
    __builtin_amdgcn_global_load_lds(
        (const __attribute__((address_space(1))) unsigned int*)g,
        (__attribute__((address_space(3))) unsigned int*)l, 16, 0, 0);
}

__device__ __forceinline__ void wg_barrier()
{
    asm volatile("" ::: "memory");
    __builtin_amdgcn_s_barrier();
    asm volatile("" ::: "memory");
}

// ---- counted-vmcnt double-buffered GEMM core: 256 thr, tile 128x128, BK=32
// (used by gemm1, rhw)
__device__ __forceinline__ void gemm_core_db(
    const bf16* __restrict__ A, int lda,
    const bf16* __restrict__ B, int ldb,
    int K, f32x4 (&acc)[4][4])
{
    __shared__ bf16 As[2][128 * 32];
    __shared__ bf16 Bs[2][128 * 32];
    const int tid = threadIdx.x;
    const int wave = tid >> 6;
    const int lane = tid & 63;
    const int lm = lane & 15;
    const int kq = lane >> 4;
    const int m0 = (wave >> 1) * 64;
    const int n0 = (wave & 1) * 64;
    const int srow = tid >> 2;
    const int skoff = (((tid & 3) ^ ((tid >> 3) & 3))) * 8;
    const int krd = (kq ^ ((lm >> 1) & 3)) * 8;
    zero_acc(acc);
    const bf16* ga = A + (size_t)srow * lda + skoff;
    const bf16* gb = B + (size_t)srow * ldb + skoff;
    load_lds16(ga, As[0] + tid * 8);
    load_lds16(ga + (size_t)64 * lda, As[0] + tid * 8 + 64 * 32);
    load_lds16(gb, Bs[0] + tid * 8);
    load_lds16(gb + (size_t)64 * ldb, Bs[0] + tid * 8 + 64 * 32);
    const int nt = K >> 5;
    for (int t = 0; t < nt; ++t) {
        const int cur = t & 1;
        if (t + 1 < nt) {
            const bf16* na = ga + (t + 1) * 32;
            const bf16* nb = gb + (t + 1) * 32;
            bf16* dA = As[cur ^ 1] + tid * 8;
            bf16* dB = Bs[cur ^ 1] + tid * 8;
            load_lds16(na, dA);
            load_lds16(na + (size_t)64 * lda, dA + 64 * 32);
            load_lds16(nb, dB);
            load_lds16(nb + (size_t)64 * ldb, dB + 64 * 32);
            asm volatile("s_waitcnt vmcnt(4)" ::: "memory");
        } else {
            asm volatile("s_waitcnt vmcnt(0)" ::: "memory");
        }
        wg_barrier();
        const bf16* as = As[cur];
        const bf16* bs = Bs[cur];
        bf16x8 av[4], bv[4];
#pragma unroll
        for (int tt = 0; tt < 4; ++tt)
            av[tt] = *(const bf16x8*)(as + (m0 + tt * 16 + lm) * 32 + krd);
#pragma unroll
        for (int tt = 0; tt < 4; ++tt)
            bv[tt] = *(const bf16x8*)(bs + (n0 + tt * 16 + lm) * 32 + krd);
#pragma unroll
        for (int i = 0; i < 4; ++i)
#pragma unroll
            for (int j = 0; j < 4; ++j)
                acc[i][j] = __builtin_amdgcn_mfma_f32_16x16x32_bf16(
                    av[i], bv[j], acc[i][j], 0, 0, 0);
        wg_barrier();
    }
}

// ---- 256x256 / BK=64 / 512-thread (8-wave, 2m x 4n) GEMM core.
// Per wave: 128x64 output, acc[8][4]; 64 MFMA per K-step.
// LDS slot (row, chunk) holds global chunk ^ (row&7) [3-bit XOR swizzle].
__device__ __forceinline__ void gemm_core_256(
    const bf16* __restrict__ A, int lda,
    const bf16* __restrict__ B, int ldb,
    int K, f32x4 (&acc)[8][4])
{
    __shared__ bf16 As[2][16384];   // [256][64] per buffer
    __shared__ bf16 Bs[2][16384];
    const int tid = threadIdx.x;
    const int lane = tid & 63;
    const int wid = tid >> 6;
    const int wm = wid >> 2, wn = wid & 3;
    const int lm = lane & 15, kq = lane >> 4;
    const int srow = tid >> 3;
    const int skoff = ((tid & 7) ^ (srow & 7)) * 8;
    const bf16* ga = A + (size_t)srow * lda + skoff;
    const bf16* gb = B + (size_t)srow * ldb + skoff;
#pragma unroll
    for (int r = 0; r < 4; ++r)
        load_lds16(ga + (size_t)(64 * r) * lda, As[0] + tid * 8 + r * 4096);
#pragma unroll
    for (int r = 0; r < 4; ++r)
        load_lds16(gb + (size_t)(64 * r) * ldb, Bs[0] + tid * 8 + r * 4096);
#pragma unroll
    for (int i = 0; i < 8; ++i)
#pragma unroll
        for (int j = 0; j < 4; ++j)
            acc[i][j] = (f32x4){0.f, 0.f, 0.f, 0.f};
    const int nt = K >> 6;
    for (int t = 0; t < nt; ++t) {
        const int cur = t & 1;
        if (t + 1 < nt) {
            const bf16* na = ga + (t + 1) * 64;
            const bf16* nb = gb + (t + 1) * 64;
#pragma unroll
            for (int r = 0; r < 4; ++r)
                load_lds16(na + (size_t)(64 * r) * lda,
                           As[cur ^ 1] + tid * 8 + r * 4096);
#pragma unroll
            for (int r = 0; r < 4; ++r)
                load_lds16(nb + (size_t)(64 * r) * ldb,
                           Bs[cur ^ 1] + tid * 8 + r * 4096);
            asm volatile("s_waitcnt vmcnt(8)" ::: "memory");
        } else {
            asm volatile("s_waitcnt vmcnt(0)" ::: "memory");
        }
        wg_barrier();
        const bf16* as = As[cur];
        const bf16* bs = Bs[cur];
#pragma unroll
        for (int ks = 0; ks < 2; ++ks) {
            bf16x8 av[8], bv[4];
#pragma unroll
            for (int i = 0; i < 8; ++i) {
                int lr = wm * 128 + i * 16 + lm;
                av[i] = *(const bf16x8*)(as + lr * 64 +
                                         (((ks << 2) | kq) ^ (lr & 7)) * 8);
            }
#pragma unroll
            for (int j = 0; j < 4; ++j) {
                int lr = wn * 64 + j * 16 + lm;
                bv[j] = *(const bf16x8*)(bs + lr * 64 +
                                         (((ks << 2) | kq) ^ (lr & 7)) * 8);
            }
#pragma unroll
            for (int i = 0; i < 8; ++i)
#pragma unroll
                for (int j = 0; j < 4; ++j)
                    acc[i][j] = __builtin_amdgcn_mfma_f32_16x16x32_bf16(
                        av[i], bv[j], acc[i][j], 0, 0, 0);
        }
        wg_barrier();
    }
}

// ------------------------------ prep kernels -------------------------------

__global__ __launch_bounds__(256) void prep_misc_kernel(
    const float* __restrict__ cv1_w,
    const float* __restrict__ qw, const float* __restrict__ qb,
    const float* __restrict__ kw, const float* __restrict__ kb,
    const float* __restrict__ vw, const float* __restrict__ vb,
    const float* __restrict__ ew, const float* __restrict__ eb,
    const float* __restrict__ cv2_w,
    const float* __restrict__ g1, const float* __restrict__ b1,
    const float* __restrict__ m1, const float* __restrict__ v1,
    const float* __restrict__ g2, const float* __restrict__ b2,
    const float* __restrict__ m2, const float* __restrict__ v2,
    const float* __restrict__ rel_h, const float* __restrict__ rel_w,
    bf16* __restrict__ w1b, bf16* __restrict__ wqkve, bf16* __restrict__ w2b,
    bf16* __restrict__ posT,
    float* __restrict__ biasq,
    float* __restrict__ bn1s, float* __restrict__ bn1h,
    float* __restrict__ bn2s, float* __restrict__ bn2h)
{
    int idx = blockIdx.x * 256 + threadIdx.x;
    if (idx < 131072) { w1b[idx] = (bf16)cv1_w[idx]; return; }
    idx -= 131072;
    if (idx < 262144) {
        int j = idx >> 8, c = idx & 255;
        int p = j >> 8, r = j & 255;
        const float* w = (p == 0) ? qw : (p == 1) ? kw : (p == 2) ? vw : ew;
        wqkve[idx] = (bf16)w[r * 256 + c];
        return;
    }
    idx -= 262144;
    if (idx < 131072) { w2b[idx] = (bf16)cv2_w[idx]; return; }
    idx -= 131072;
    if (idx < 1024) {
        int p = idx >> 8, r = idx & 255;
        const float* bb = (p == 0) ? qb : (p == 1) ? kb : (p == 2) ? vb : eb;
        biasq[idx] = bb[r];
        return;
    }
    idx -= 1024;
    if (idx < 256) {
        float s = g1[idx] * rsqrtf(v1[idx] + 1e-5f);
        bn1s[idx] = s;
        bn1h[idx] = b1[idx] - m1[idx] * s;
        return;
    }
    idx -= 256;
    if (idx < 512) {
        float s = g2[idx] * rsqrtf(v2[idx] + 1e-5f);
        bn2s[idx] = s;
        bn2h[idx] = b2[idx] - m2[idx] * s;
        return;
    }
    idx -= 512;
    if (idx < 32768) {
        int r = idx >> 8, c = idx & 255;
        posT[idx] = (bf16)((r < 64) ? rel_h[c * 64 + r] : rel_w[c * 64 + (r - 64)]);
        return;
    }
}

__global__ __launch_bounds__(256) void zero_lsum_kernel(float* __restrict__ p)
{
    p[blockIdx.x * 256 + threadIdx.x] = 0.f;
}

// xt[b*4096+n][d] = (bf16) x[b][d][n]
__global__ __launch_bounds__(256) void transpose_x_kernel(
    const float* __restrict__ x, bf16* __restrict__ xt)
{
    __shared__ float tile[64][65];
    int b = blockIdx.z;
    int n0 = blockIdx.x * 64;
    int d0 = blockIdx.y * 64;
    int tx = threadIdx.x & 63, ty = threadIdx.x >> 6;
#pragma unroll
    for (int i = 0; i < 16; ++i) {
        int d = i * 4 + ty;
        tile[d][tx] = x[((size_t)(b * 512 + d0 + d)) * 4096 + n0 + tx];
    }
    __syncthreads();
#pragma unroll
    for (int i = 0; i < 16; ++i) {
        int n = i * 4 + ty;
        xt[((size_t)(b * 4096 + n0 + n)) * 512 + d0 + tx] = (bf16)tile[tx][n];
    }
}

// v_cm[b][c][m] = v_nm[b*4096+m][c]
__global__ __launch_bounds__(256) void transpose_v_kernel(
    const bf16* __restrict__ v_nm, bf16* __restrict__ v_cm)
{
    __shared__ float tile[64][65];
    int b = blockIdx.z;
    int m0 = blockIdx.x * 64;
    int c0 = blockIdx.y * 64;
    int tx = threadIdx.x & 63, ty = threadIdx.x >> 6;
#pragma unroll
    for (int i = 0; i < 16; ++i) {
        int m = i * 4 + ty;
        tile[m][tx] = (float)v_nm[((size_t)(b * 4096 + m0 + m)) * 256 + c0 + tx];
    }
    __syncthreads();
#pragma unroll
    for (int i = 0; i < 16; ++i) {
        int c = i * 4 + ty;
        v_cm[((size_t)(b * 256 + c0 + c)) * 4096 + m0 + tx] = (bf16)tile[tx][c];
    }
}

// ------------------------------ GEMM kernels -------------------------------

__global__ __launch_bounds__(256) void gemm1_kernel(
    const bf16* __restrict__ xt, const bf16* __restrict__ w1b,
    const float* __restrict__ bn1s, const float* __restrict__ bn1h,
    bf16* __restrict__ x1t)
{
    const bf16* A = xt + (size_t)(blockIdx.y * 128) * 512;
    const bf16* Bm = w1b + (size_t)(blockIdx.x * 128) * 512;
    f32x4 acc[4][4];
    gemm_core_db(A, 512, Bm, 512, 512, acc);
    int wave = threadIdx.x >> 6;
    int lane = threadIdx.x & 63;
    int m0 = blockIdx.y * 128 + (wave >> 1) * 64;
    int n0 = blockIdx.x * 128 + (wave & 1) * 64;
    int lm = lane & 15, kq = lane >> 4;
#pragma unroll
    for (int i = 0; i < 4; ++i)
#pragma unroll
        for (int j = 0; j < 4; ++j)
#pragma unroll
            for (int r = 0; r < 4; ++r) {
                int row = m0 + i * 16 + kq * 4 + r;
                int col = n0 + j * 16 + lm;
                float h = bn1s[col] * acc[i][j][r] + bn1h[col];
                x1t[(size_t)row * 256 + col] = (bf16)silu_f(h);
            }
}

// projections on the 256^2 core: bx=0,1 -> qk cols 0..511; bx=2 -> v; bx=3 -> e
__global__ __launch_bounds__(512, 1) void gemm2_kernel(
    const bf16* __restrict__ x1t, const bf16* __restrict__ wqkve,
    const float* __restrict__ biasq,
    bf16* __restrict__ qk, bf16* __restrict__ v_nm, bf16* __restrict__ e_nm)
{
    const int bx = blockIdx.x, by = blockIdx.y;
    const bf16* A = x1t + (size_t)(by * 256) * 256;
    const bf16* Bm = wqkve + (size_t)(bx * 256) * 256;
    f32x4 acc[8][4];
    gemm_core_256(A, 256, Bm, 256, 256, acc);
    const int tid = threadIdx.x, lane = tid & 63, wid = tid >> 6;
    const int wm = wid >> 2, wn = wid & 3, lm = lane & 15, kq = lane >> 4;
#pragma unroll
    for (int i = 0; i < 8; ++i)
#pragma unroll
        for (int j = 0; j < 4; ++j)
#pragma unroll
            for (int r = 0; r < 4; ++r) {
                int row = by * 256 + wm * 128 + i * 16 + kq * 4 + r;
                int col = bx * 256 + wn * 64 + j * 16 + lm;
                bf16 val = (bf16)(acc[i][j][r] + biasq[col]);
                if (bx < 2)          qk[(size_t)row * 512 + col] = val;
                else if (bx == 2)    v_nm[(size_t)row * 256 + (col - 512)] = val;
                else                 e_nm[(size_t)row * 256 + (col - 768)] = val;
            }
}

// rhwT[b][m][r] = sum_c posT[r][c] * e_nm[b*4096+m][c]  (r<64: RH, r>=64: RW)
__global__ __launch_bounds__(256) void gemm_rhw_kernel(
    const bf16* __restrict__ posT, const bf16* __restrict__ e_nm,
    bf16* __restrict__ rhwT)
{
    int b = blockIdx.z;
    const bf16* A = e_nm + ((size_t)b * 4096 + blockIdx.x * 128) * 256;
    f32x4 acc[4][4];
    gemm_core_db(A, 256, posT, 256, 256, acc);
    int wave = threadIdx.x >> 6;
    int lane = threadIdx.x & 63;
    int m0 = (wave >> 1) * 64, n0 = (wave & 1) * 64;
    int lm = lane & 15, kq = lane >> 4;
    bf16* rb = rhwT + ((size_t)b * 4096 + blockIdx.x * 128) * 128;
#pragma unroll
    for (int i = 0; i < 4; ++i)
#pragma unroll
        for (int j = 0; j < 4; ++j)
#pragma unroll
            for (int r = 0; r < 4; ++r)
                rb[(size_t)(m0 + i * 16 + kq * 4 + r) * 128 + n0 + j * 16 + lm] =
                    (bf16)acc[i][j][r];
}

// P[bz][n][m] = exp(q.k + RH + RW - 8), bf16; row sums -> lsum[bz][n]
__global__ __launch_bounds__(512, 1) void gemm3b_kernel(
    const bf16* __restrict__ qk, const bf16* __restrict__ rhwT,
    bf16* __restrict__ P, float* __restrict__ lsum, int gbase)
{
    __shared__ float rs[256];
    // XCD-aware bijective swizzle (1024 blocks % 8 == 0)
    int flat = blockIdx.x + 16 * blockIdx.y + 256 * blockIdx.z;
    flat = (flat & 7) * 128 + (flat >> 3);
    const int bx = flat & 15, by = (flat >> 4) & 15, bz = flat >> 8;
    const int b = gbase + bz;
    const int tid = threadIdx.x;
    const int wid = tid >> 6;
    const int lane = tid & 63;
    const int wm = wid >> 2, wn = wid & 3;
    const int lm = lane & 15, kq = lane >> 4;
    const bf16* A = qk + ((size_t)b * 4096 + by * 256) * 512;        // q rows
    const bf16* Bm = qk + ((size_t)b * 4096 + bx * 256) * 512 + 256; // k rows
    f32x4 acc[8][4];
    gemm_core_256(A, 512, Bm, 512, 256, acc);
    // ---- positional terms
    bf16x2 rhv2[4];
    bf16x4 rwv[4][4];
    {
        const bf16* rbT = rhwT + ((size_t)b * 4096 + bx * 256) * 128;
#pragma unroll
        for (int j = 0; j < 4; ++j) {
            const bf16* cp = rbT + (size_t)(wn * 64 + j * 16 + lm) * 128;
            rhv2[j] = *(const bf16x2*)(cp + by * 4 + wm * 2);
#pragma unroll
            for (int ii = 0; ii < 4; ++ii)
                rwv[j][ii] = *(const bf16x4*)(cp + 64 + ii * 16 + kq * 4);
        }
    }
    if (tid < 256) rs[tid] = 0.f;
    __syncthreads();
    // exp + per-lane row partials
    float ps[8][4];
#pragma unroll
    for (int i = 0; i < 8; ++i)
#pragma unroll
        for (int r = 0; r < 4; ++r) {
            float s = 0.f;
#pragma unroll
            for (int j = 0; j < 4; ++j) {
                float sv = acc[i][j][r] + (float)rhv2[j][i >> 2]
                                        + (float)rwv[j][i & 3][r];
                float e = __expf(sv - 8.f);
                acc[i][j][r] = e;
                s += e;
            }
            ps[i][r] = s;
        }
#pragma unroll
    for (int msk = 1; msk < 16; msk <<= 1)
#pragma unroll
        for (int i = 0; i < 8; ++i)
#pragma unroll
            for (int r = 0; r < 4; ++r)
                ps[i][r] += __shfl_xor(ps[i][r], msk);
    if (lm == 0) {
#pragma unroll
        for (int i = 0; i < 8; ++i)
#pragma unroll
            for (int r = 0; r < 4; ++r)
                atomicAdd(&rs[wm * 128 + i * 16 + kq * 4 + r], ps[i][r]);
    }
    // store exp(S) tile
    bf16* Pb = P + ((size_t)bz * 4096 + by * 256) * 4096 + bx * 256;
#pragma unroll
    for (int i = 0; i < 8; ++i)
#pragma unroll
        for (int j = 0; j < 4; ++j)
#pragma unroll
            for (int r = 0; r < 4; ++r)
                Pb[(size_t)(wm * 128 + i * 16 + kq * 4 + r) * 4096
                   + wn * 64 + j * 16 + lm] = (bf16)acc[i][j][r];
    __syncthreads();
    if (tid < 256)
        atomicAdd(&lsum[(size_t)bz * 4096 + by * 256 + tid], rs[tid]);
}

// split-K=4 PV on the 256^2 core: all 256 cols per block.
// pacc[kc][bz*4096+n][c] = sum_{m in kc chunk} P[bz][n][m]*v_cm[b][c][m]
__global__ __launch_bounds__(512, 1) void gemm4b_kernel(
    const bf16* __restrict__ P, const bf16* __restrict__ v_cm,
    bf16* __restrict__ pacc, int gbase)
{
    // XCD-aware bijective swizzle (256 blocks): XCD gets fixed bz -> v_cm[b]
    // slice stays L2-resident.
    int flat = blockIdx.x + 16 * blockIdx.y + 64 * blockIdx.z;
    flat = (flat & 7) * 32 + (flat >> 3);
    const int by = flat & 15, kc = (flat >> 4) & 3, bz = flat >> 6;
    const int b = gbase + bz;
    const bf16* A = P + ((size_t)bz * 4096 + by * 256) * 4096 + kc * 1024;
    const bf16* Bm = v_cm + (size_t)b * 256 * 4096 + kc * 1024;
    f32x4 acc[8][4];
    gemm_core_256(A, 4096, Bm, 4096, 1024, acc);
    const int tid = threadIdx.x, lane = tid & 63, wid = tid >> 6;
    const int wm = wid >> 2, wn = wid & 3, lm = lane & 15, kq = lane >> 4;
    bf16* ob = pacc + ((size_t)kc * 16384 + bz * 4096 + by * 256) * 256;
#pragma unroll
    for (int i = 0; i < 8; ++i)
#pragma unroll
        for (int r = 0; r < 4; ++r)
#pragma unroll
            for (int j = 0; j < 4; ++j)
                ob[(size_t)(wm * 128 + i * 16 + kq * 4 + r) * 256
                   + wn * 64 + j * 16 + lm] = (bf16)acc[i][j][r];
}

// out_t[(gbase*4096)+row][c] = (sum_kc pacc[kc][row][c]) / lsum[row]
__global__ __launch_bounds__(256) void reduce4_kernel(
    const bf16* __restrict__ pacc, const float* __restrict__ lsum,
    bf16* __restrict__ out_t, int gbase)
{
    int t = blockIdx.x * 256 + threadIdx.x;   // 524288 threads
    int row = t >> 5;                          // 0..16383
    int c0 = (t & 31) * 8;
    bf16x8 p0 = *(const bf16x8*)(pacc + (size_t)row * 256 + c0);
    bf16x8 p1 = *(const bf16x8*)(pacc + (size_t)(16384 + row) * 256 + c0);
    bf16x8 p2 = *(const bf16x8*)(pacc + (size_t)(32768 + row) * 256 + c0);
    bf16x8 p3 = *(const bf16x8*)(pacc + (size_t)(49152 + row) * 256 + c0);
    float inv = 1.f / lsum[row];
    bf16x8 o;
#pragma unroll
    for (int e = 0; e < 8; ++e)
        o[e] = (bf16)((((float)p0[e] + (float)p1[e]) +
                       ((float)p2[e] + (float)p3[e])) * inv);
    *(bf16x8*)(out_t + ((size_t)gbase * 4096 + row) * 256 + c0) = o;
}

// d_out[b][d][n] = x[b][d][n] + silu(bn2( sum_c w2b[d][c]*out_t[b*4096+n][c] ))
__global__ __launch_bounds__(512, 1) void gemm5_kernel(
    const bf16* __restrict__ w2b, const bf16* __restrict__ out_t,
    const float* __restrict__ bn2s, const float* __restrict__ bn2h,
    const float* __restrict__ x, float* __restrict__ out)
{
    int b = blockIdx.z;
    const bf16* A = w2b + (size_t)(blockIdx.y * 256) * 256;              // d rows
    const bf16* Bm = out_t + ((size_t)b * 4096 + blockIdx.x * 256) * 256; // n rows
    f32x4 acc[8][4];
    gemm_core_256(A, 256, Bm, 256, 256, acc);
    const int tid = threadIdx.x, lane = tid & 63, wid = tid >> 6;
    const int wm = wid >> 2, wn = wid & 3, lm = lane & 15, kq = lane >> 4;
#pragma unroll
    for (int i = 0; i < 8; ++i)
#pragma unroll
        for (int j = 0; j < 4; ++j)
#pragma unroll
            for (int r = 0; r < 4; ++r) {
                int d = blockIdx.y * 256 + wm * 128 + i * 16 + kq * 4 + r;
                int n = blockIdx.x * 256 + wn * 64 + j * 16 + lm;
                float h = bn2s[d] * acc[i][j][r] + bn2h[d];
                size_t gi = ((size_t)(b * 512 + d)) * 4096 + n;
                out[gi] = x[gi] + silu_f(h);
            }
}

// ------------------------------- launcher ----------------------------------

extern "C" void kernel_launch(void* const* d_in, const int* in_sizes, int n_in,
                              void* d_out, int out_size, void* d_ws, size_t ws_size,
                              hipStream_t stream)
{
    (void)in_sizes; (void)n_in; (void)out_size; (void)ws_size;
    const float* x     = (const float*)d_in[0];
    const float* cv1_w = (const float*)d_in[1];
    const float* bn1_g = (const float*)d_in[2];
    const float* bn1_b = (const float*)d_in[3];
    const float* bn1_m = (const float*)d_in[4];
    const float* bn1_v = (const float*)d_in[5];
    const float* q_w   = (const float*)d_in[6];
    const float* q_b   = (const float*)d_in[7];
    const float* k_w   = (const float*)d_in[8];
    const float* k_b   = (const float*)d_in[9];
    const float* v_w   = (const float*)d_in[10];
    const float* v_b   = (const float*)d_in[11];
    const float* e_w   = (const float*)d_in[12];
    const float* e_b   = (const float*)d_in[13];
    const float* rel_h = (const float*)d_in[14];
    const float* rel_w = (const float*)d_in[15];
    const float* cv2_w = (const float*)d_in[16];
    const float* bn2_g = (const float*)d_in[17];
    const float* bn2_b = (const float*)d_in[18];
    const float* bn2_m = (const float*)d_in[19];
    const float* bn2_v = (const float*)d_in[20];
    float* out = (float*)d_out;

    char* ws = (char*)d_ws;
    bf16* P     = (bf16*)(ws + 0);            // 128 MB [4][4096][4096]
    bf16* xt    = (bf16*)(ws + 0);            //  32 MB overlay
    bf16* x1t   = (bf16*)(ws + 33554432);     //  16 MB overlay
    bf16* v_nm  = (bf16*)(ws + 50331648);     //  16 MB overlay
    bf16* e_nm  = (bf16*)(ws + 67108864);     //  16 MB overlay
    bf16* qk    = (bf16*)(ws + 134217728);    //  32 MB [32768][512] (q|k)
    bf16* v_cm  = (bf16*)(ws + 167772160);    //  16 MB [8][256][4096]
    bf16* rhwT  = (bf16*)(ws + 184549376);    //   8 MB [8][4096][128]
    bf16* out_t = (bf16*)(ws + 192937984);    //  16 MB [32768][256]
    bf16* w1b   = (bf16*)(ws + 209715200);    // 256 KB
    bf16* wqkve = (bf16*)(ws + 209977344);    // 512 KB
    bf16* w2b   = (bf16*)(ws + 210501632);    // 256 KB
    bf16* posT  = (bf16*)(ws + 210763776);    //  64 KB [128][256]
    float* biasq= (float*)(ws + 210829312);   //   4 KB
    float* bn1s = (float*)(ws + 210833408);
    float* bn1h = (float*)(ws + 210834432);
    float* bn2s = (float*)(ws + 210835456);
    float* bn2h = (float*)(ws + 210837504);
    float* lsum = (float*)(ws + 210839552);   // 128 KB [2][4][4096] fp32
    // pacc (32 MB, [4][16384][256] bf16) lives in d_out: it is dead after
    // reduce4, and gemm5 (the only writer of d_out) runs strictly after.
    bf16* pacc  = (bf16*)d_out;

    prep_misc_kernel<<<2183, 256, 0, stream>>>(
        cv1_w, q_w, q_b, k_w, k_b, v_w, v_b, e_w, e_b, cv2_w,
        bn1_g, bn1_b, bn1_m, bn1_v, bn2_g, bn2_b, bn2_m, bn2_v,
        rel_h, rel_w,
        w1b, wqkve, w2b, posT, biasq, bn1s, bn1h, bn2s, bn2h);
    zero_lsum_kernel<<<128, 256, 0, stream>>>(lsum);
    transpose_x_kernel<<<dim3(64, 8, 8), 256, 0, stream>>>(x, xt);
    gemm1_kernel<<<dim3(2, 256), 256, 0, stream>>>(xt, w1b, bn1s, bn1h, x1t);
    gemm2_kernel<<<dim3(4, 128), 512, 0, stream>>>(x1t, wqkve, biasq, qk, v_nm, e_nm);
    gemm_rhw_kernel<<<dim3(32, 1, 8), 256, 0, stream>>>(posT, e_nm, rhwT);
    transpose_v_kernel<<<dim3(64, 4, 8), 256, 0, stream>>>(v_nm, v_cm);
    for (int g = 0; g < 2; ++g) {
        float* ls = lsum + (size_t)g * 4 * 4096;
        gemm3b_kernel<<<dim3(16, 16, 4), 512, 0, stream>>>(qk, rhwT, P, ls, g * 4);
        gemm4b_kernel<<<dim3(16, 4, 4), 512, 0, stream>>>(P, v_cm, pacc, g * 4);
        reduce4_kernel<<<2048, 256, 0, stream>>>(pacc, ls, out_t, g * 4);
    }
    gemm5_kernel<<<dim3(16, 2, 8), 512, 0, stream>>>(w2b, out_t, bn2s, bn2h, x, out);
}

// Round 7
// 532.614 us; speedup vs baseline: 1.3155x; 1.0053x over previous
//
#include <hip/hip_runtime.h>

// ---------------------------------------------------------------------------
// ExtraPositionPromptSABottleneck on MI355X (gfx950)
// B=8, DIMS=512, C=256, H=W=64, N=4096.
//
// Round 11:
//  - LDS-staged coalesced epilogues for the 256^2-core GEMMs (gemm2/3b/4b):
//    round-10 counters showed gemm3b running AT its achieved 2.0 TB/s --
//    and that BW was capped by 128 scalar 2B stores/thread (scattered 32B
//    segments).  Now: fragments -> padded LDS tile (stride 260, all-bank
//    scalar writes) -> barrier -> 16x{ds_read_b128 + global_store_dwordx4}
//    per thread (1KB contiguous per wave-instruction).
//  - s_setprio(1/0) around MFMA clusters in the 256^2 core (T5).
//  - Core takes caller-provided LDS so the epilogue can reuse it.
// ---------------------------------------------------------------------------

typedef __bf16 bf16;
typedef __attribute__((ext_vector_type(8))) __bf16 bf16x8;
typedef __attribute__((ext_vector_type(4))) __bf16 bf16x4;
typedef __attribute__((ext_vector_type(2))) __bf16 bf16x2;
typedef __attribute__((ext_vector_type(4))) float f32x4;

__device__ __forceinline__ float silu_f(float x) { return x / (1.f + __expf(-x)); }

__device__ __forceinline__ void zero_acc(f32x4 (&acc)[4][4])
{
#pragma unroll
    for (int i = 0; i < 4; ++i)
#pragma unroll
        for (int j = 0; j < 4; ++j)
            acc[i][j] = (f32x4){0.f, 0.f, 0.f, 0.f};
}

__device__ __forceinline__ void load_lds16(const bf16* g, bf16* l)
{
    __builtin_amdgcn_global_load_lds(
        (const __attribute__((address_space(1))) unsigned int*)g,
        (__attribute__((address_space(3))) unsigned int*)l, 16, 0, 0);
}

__device__ __forceinline__ void wg_barrier()
{
    asm volatile("" ::: "memory");
    __builtin_amdgcn_s_barrier();
    asm volatile("" ::: "memory");
}

// ---- counted-vmcnt double-buffered GEMM core: 256 thr, tile 128x128, BK=32
// (used by gemm1, rhw)
__device__ __forceinline__ void gemm_core_db(
    const bf16* __restrict__ A, int lda,
    const bf16* __restrict__ B, int ldb,
    int K, f32x4 (&acc)[4][4])
{
    __shared__ bf16 As[2][128 * 32];
    __shared__ bf16 Bs[2][128 * 32];
    const int tid = threadIdx.x;
    const int wave = tid >> 6;
    const int lane = tid & 63;
    const int lm = lane & 15;
    const int kq = lane >> 4;
    const int m0 = (wave >> 1) * 64;
    const int n0 = (wave & 1) * 64;
    const int srow = tid >> 2;
    const int skoff = (((tid & 3) ^ ((tid >> 3) & 3))) * 8;
    const int krd = (kq ^ ((lm >> 1) & 3)) * 8;
    zero_acc(acc);
    const bf16* ga = A + (size_t)srow * lda + skoff;
    const bf16* gb = B + (size_t)srow * ldb + skoff;
    load_lds16(ga, As[0] + tid * 8);
    load_lds16(ga + (size_t)64 * lda, As[0] + tid * 8 + 64 * 32);
    load_lds16(gb, Bs[0] + tid * 8);
    load_lds16(gb + (size_t)64 * ldb, Bs[0] + tid * 8 + 64 * 32);
    const int nt = K >> 5;
    for (int t = 0; t < nt; ++t) {
        const int cur = t & 1;
        if (t + 1 < nt) {
            const bf16* na = ga + (t + 1) * 32;
            const bf16* nb = gb + (t + 1) * 32;
            bf16* dA = As[cur ^ 1] + tid * 8;
            bf16* dB = Bs[cur ^ 1] + tid * 8;
            load_lds16(na, dA);
            load_lds16(na + (size_t)64 * lda, dA + 64 * 32);
            load_lds16(nb, dB);
            load_lds16(nb + (size_t)64 * ldb, dB + 64 * 32);
            asm volatile("s_waitcnt vmcnt(4)" ::: "memory");
        } else {
            asm volatile("s_waitcnt vmcnt(0)" ::: "memory");
        }
        wg_barrier();
        const bf16* as = As[cur];
        const bf16* bs = Bs[cur];
        bf16x8 av[4], bv[4];
#pragma unroll
        for (int tt = 0; tt < 4; ++tt)
            av[tt] = *(const bf16x8*)(as + (m0 + tt * 16 + lm) * 32 + krd);
#pragma unroll
        for (int tt = 0; tt < 4; ++tt)
            bv[tt] = *(const bf16x8*)(bs + (n0 + tt * 16 + lm) * 32 + krd);
#pragma unroll
        for (int i = 0; i < 4; ++i)
#pragma unroll
            for (int j = 0; j < 4; ++j)
                acc[i][j] = __builtin_amdgcn_mfma_f32_16x16x32_bf16(
                    av[i], bv[j], acc[i][j], 0, 0, 0);
        wg_barrier();
    }
}

// ---- 256x256 / BK=64 / 512-thread (8-wave, 2m x 4n) GEMM core.
// As/Bs: caller-provided LDS, 2*16384 bf16 each (double-buffered).
__device__ __forceinline__ void gemm_core_256(
    const bf16* __restrict__ A, int lda,
    const bf16* __restrict__ B, int ldb,
    int K, f32x4 (&acc)[8][4], bf16* As, bf16* Bs)
{
    const int tid = threadIdx.x;
    const int lane = tid & 63;
    const int wid = tid >> 6;
    const int wm = wid >> 2, wn = wid & 3;
    const int lm = lane & 15, kq = lane >> 4;
    const int srow = tid >> 3;
    const int skoff = ((tid & 7) ^ (srow & 7)) * 8;
    const bf16* ga = A + (size_t)srow * lda + skoff;
    const bf16* gb = B + (size_t)srow * ldb + skoff;
#pragma unroll
    for (int r = 0; r < 4; ++r)
        load_lds16(ga + (size_t)(64 * r) * lda, As + tid * 8 + r * 4096);
#pragma unroll
    for (int r = 0; r < 4; ++r)
        load_lds16(gb + (size_t)(64 * r) * ldb, Bs + tid * 8 + r * 4096);
#pragma unroll
    for (int i = 0; i < 8; ++i)
#pragma unroll
        for (int j = 0; j < 4; ++j)
            acc[i][j] = (f32x4){0.f, 0.f, 0.f, 0.f};
    const int nt = K >> 6;
    for (int t = 0; t < nt; ++t) {
        const int cur = t & 1;
        if (t + 1 < nt) {
            const bf16* na = ga + (t + 1) * 64;
            const bf16* nb = gb + (t + 1) * 64;
            bf16* dA = As + (cur ^ 1) * 16384;
            bf16* dB = Bs + (cur ^ 1) * 16384;
#pragma unroll
            for (int r = 0; r < 4; ++r)
                load_lds16(na + (size_t)(64 * r) * lda, dA + tid * 8 + r * 4096);
#pragma unroll
            for (int r = 0; r < 4; ++r)
                load_lds16(nb + (size_t)(64 * r) * ldb, dB + tid * 8 + r * 4096);
            asm volatile("s_waitcnt vmcnt(8)" ::: "memory");
        } else {
            asm volatile("s_waitcnt vmcnt(0)" ::: "memory");
        }
        wg_barrier();
        const bf16* as = As + cur * 16384;
        const bf16* bs = Bs + cur * 16384;
#pragma unroll
        for (int ks = 0; ks < 2; ++ks) {
            bf16x8 av[8], bv[4];
#pragma unroll
            for (int i = 0; i < 8; ++i) {
                int lr = wm * 128 + i * 16 + lm;
                av[i] = *(const bf16x8*)(as + lr * 64 +
                                         (((ks << 2) | kq) ^ (lr & 7)) * 8);
            }
#pragma unroll
            for (int j = 0; j < 4; ++j) {
                int lr = wn * 64 + j * 16 + lm;
                bv[j] = *(const bf16x8*)(bs + lr * 64 +
                                         (((ks << 2) | kq) ^ (lr & 7)) * 8);
            }
            __builtin_amdgcn_s_setprio(1);
#pragma unroll
            for (int i = 0; i < 8; ++i)
#pragma unroll
                for (int j = 0; j < 4; ++j)
                    acc[i][j] = __builtin_amdgcn_mfma_f32_16x16x32_bf16(
                        av[i], bv[j], acc[i][j], 0, 0, 0);
            __builtin_amdgcn_s_setprio(0);
        }
        wg_barrier();
    }
}

// ------------------------------ prep kernels -------------------------------

__global__ __launch_bounds__(256) void prep_misc_kernel(
    const float* __restrict__ cv1_w,
    const float* __restrict__ qw, const float* __restrict__ qb,
    const float* __restrict__ kw, const float* __restrict__ kb,
    const float* __restrict__ vw, const float* __restrict__ vb,
    const float* __restrict__ ew, const float* __restrict__ eb,
    const float* __restrict__ cv2_w,
    const float* __restrict__ g1, const float* __restrict__ b1,
    const float* __restrict__ m1, const float* __restrict__ v1,
    const float* __restrict__ g2, const float* __restrict__ b2,
    const float* __restrict__ m2, const float* __restrict__ v2,
    const float* __restrict__ rel_h, const float* __restrict__ rel_w,
    bf16* __restrict__ w1b, bf16* __restrict__ wqkve, bf16* __restrict__ w2b,
    bf16* __restrict__ posT,
    float* __restrict__ biasq,
    float* __restrict__ bn1s, float* __restrict__ bn1h,
    float* __restrict__ bn2s, float* __restrict__ bn2h)
{
    int idx = blockIdx.x * 256 + threadIdx.x;
    if (idx < 131072) { w1b[idx] = (bf16)cv1_w[idx]; return; }
    idx -= 131072;
    if (idx < 262144) {
        int j = idx >> 8, c = idx & 255;
        int p = j >> 8, r = j & 255;
        const float* w = (p == 0) ? qw : (p == 1) ? kw : (p == 2) ? vw : ew;
        wqkve[idx] = (bf16)w[r * 256 + c];
        return;
    }
    idx -= 262144;
    if (idx < 131072) { w2b[idx] = (bf16)cv2_w[idx]; return; }
    idx -= 131072;
    if (idx < 1024) {
        int p = idx >> 8, r = idx & 255;
        const float* bb = (p == 0) ? qb : (p == 1) ? kb : (p == 2) ? vb : eb;
        biasq[idx] = bb[r];
        return;
    }
    idx -= 1024;
    if (idx < 256) {
        float s = g1[idx] * rsqrtf(v1[idx] + 1e-5f);
        bn1s[idx] = s;
        bn1h[idx] = b1[idx] - m1[idx] * s;
        return;
    }
    idx -= 256;
    if (idx < 512) {
        float s = g2[idx] * rsqrtf(v2[idx] + 1e-5f);
        bn2s[idx] = s;
        bn2h[idx] = b2[idx] - m2[idx] * s;
        return;
    }
    idx -= 512;
    if (idx < 32768) {
        int r = idx >> 8, c = idx & 255;
        posT[idx] = (bf16)((r < 64) ? rel_h[c * 64 + r] : rel_w[c * 64 + (r - 64)]);
        return;
    }
}

__global__ __launch_bounds__(256) void zero_lsum_kernel(float* __restrict__ p)
{
    p[blockIdx.x * 256 + threadIdx.x] = 0.f;
}

// xt[b*4096+n][d] = (bf16) x[b][d][n]
__global__ __launch_bounds__(256) void transpose_x_kernel(
    const float* __restrict__ x, bf16* __restrict__ xt)
{
    __shared__ float tile[64][65];
    int b = blockIdx.z;
    int n0 = blockIdx.x * 64;
    int d0 = blockIdx.y * 64;
    int tx = threadIdx.x & 63, ty = threadIdx.x >> 6;
#pragma unroll
    for (int i = 0; i < 16; ++i) {
        int d = i * 4 + ty;
        tile[d][tx] = x[((size_t)(b * 512 + d0 + d)) * 4096 + n0 + tx];
    }
    __syncthreads();
#pragma unroll
    for (int i = 0; i < 16; ++i) {
        int n = i * 4 + ty;
        xt[((size_t)(b * 4096 + n0 + n)) * 512 + d0 + tx] = (bf16)tile[tx][n];
    }
}

// v_cm[b][c][m] = v_nm[b*4096+m][c]
__global__ __launch_bounds__(256) void transpose_v_kernel(
    const bf16* __restrict__ v_nm, bf16* __restrict__ v_cm)
{
    __shared__ float tile[64][65];
    int b = blockIdx.z;
    int m0 = blockIdx.x * 64;
    int c0 = blockIdx.y * 64;
    int tx = threadIdx.x & 63, ty = threadIdx.x >> 6;
#pragma unroll
    for (int i = 0; i < 16; ++i) {
        int m = i * 4 + ty;
        tile[m][tx] = (float)v_nm[((size_t)(b * 4096 + m0 + m)) * 256 + c0 + tx];
    }
    __syncthreads();
#pragma unroll
    for (int i = 0; i < 16; ++i) {
        int c = i * 4 + ty;
        v_cm[((size_t)(b * 256 + c0 + c)) * 4096 + m0 + tx] = (bf16)tile[tx][c];
    }
}

// ------------------------------ GEMM kernels -------------------------------

__global__ __launch_bounds__(256) void gemm1_kernel(
    const bf16* __restrict__ xt, const bf16* __restrict__ w1b,
    const float* __restrict__ bn1s, const float* __restrict__ bn1h,
    bf16* __restrict__ x1t)
{
    const bf16* A = xt + (size_t)(blockIdx.y * 128) * 512;
    const bf16* Bm = w1b + (size_t)(blockIdx.x * 128) * 512;
    f32x4 acc[4][4];
    gemm_core_db(A, 512, Bm, 512, 512, acc);
    int wave = threadIdx.x >> 6;
    int lane = threadIdx.x & 63;
    int m0 = blockIdx.y * 128 + (wave >> 1) * 64;
    int n0 = blockIdx.x * 128 + (wave & 1) * 64;
    int lm = lane & 15, kq = lane >> 4;
#pragma unroll
    for (int i = 0; i < 4; ++i)
#pragma unroll
        for (int j = 0; j < 4; ++j)
#pragma unroll
            for (int r = 0; r < 4; ++r) {
                int row = m0 + i * 16 + kq * 4 + r;
                int col = n0 + j * 16 + lm;
                float h = bn1s[col] * acc[i][j][r] + bn1h[col];
                x1t[(size_t)row * 256 + col] = (bf16)silu_f(h);
            }
}

// projections on the 256^2 core: bx=0,1 -> qk; bx=2 -> v_nm; bx=3 -> e_nm
__global__ __launch_bounds__(512, 1) void gemm2_kernel(
    const bf16* __restrict__ x1t, const bf16* __restrict__ wqkve,
    const float* __restrict__ biasq,
    bf16* __restrict__ qk, bf16* __restrict__ v_nm, bf16* __restrict__ e_nm)
{
    __shared__ bf16 smem[66560];
    const int bx = blockIdx.x, by = blockIdx.y;
    const bf16* A = x1t + (size_t)(by * 256) * 256;
    const bf16* Bm = wqkve + (size_t)(bx * 256) * 256;
    f32x4 acc[8][4];
    gemm_core_256(A, 256, Bm, 256, 256, acc, smem, smem + 32768);
    const int tid = threadIdx.x, lane = tid & 63, wid = tid >> 6;
    const int wm = wid >> 2, wn = wid & 3, lm = lane & 15, kq = lane >> 4;
    // stage to LDS (stride 260) with bias applied
#pragma unroll
    for (int j = 0; j < 4; ++j) {
        float bq = biasq[bx * 256 + wn * 64 + j * 16 + lm];
#pragma unroll
        for (int i = 0; i < 8; ++i)
#pragma unroll
            for (int r = 0; r < 4; ++r)
                smem[(wm * 128 + i * 16 + kq * 4 + r) * 260
                     + wn * 64 + j * 16 + lm] = (bf16)(acc[i][j][r] + bq);
    }
    __syncthreads();
    char* base;
    size_t rstride;
    if (bx < 2)       { base = (char*)(qk + (size_t)(by * 256) * 512 + bx * 256); rstride = 1024; }
    else if (bx == 2) { base = (char*)(v_nm + (size_t)(by * 256) * 256); rstride = 512; }
    else              { base = (char*)(e_nm + (size_t)(by * 256) * 256); rstride = 512; }
    const char* Sl = (const char*)smem;
#pragma unroll
    for (int c = 0; c < 16; ++c) {
        int o = c * 8192 + tid * 16;
        int row = o >> 9, colb = o & 511;
        bf16x8 v = *(const bf16x8*)(Sl + row * 520 + colb);
        *(bf16x8*)(base + (size_t)row * rstride + colb) = v;
    }
}

// rhwT[b][m][r] = sum_c posT[r][c] * e_nm[b*4096+m][c]  (r<64: RH, r>=64: RW)
__global__ __launch_bounds__(256) void gemm_rhw_kernel(
    const bf16* __restrict__ posT, const bf16* __restrict__ e_nm,
    bf16* __restrict__ rhwT)
{
    int b = blockIdx.z;
    const bf16* A = e_nm + ((size_t)b * 4096 + blockIdx.x * 128) * 256;
    f32x4 acc[4][4];
    gemm_core_db(A, 256, posT, 256, 256, acc);
    int wave = threadIdx.x >> 6;
    int lane = threadIdx.x & 63;
    int m0 = (wave >> 1) * 64, n0 = (wave & 1) * 64;
    int lm = lane & 15, kq = lane >> 4;
    bf16* rb = rhwT + ((size_t)b * 4096 + blockIdx.x * 128) * 128;
#pragma unroll
    for (int i = 0; i < 4; ++i)
#pragma unroll
        for (int j = 0; j < 4; ++j)
#pragma unroll
            for (int r = 0; r < 4; ++r)
                rb[(size_t)(m0 + i * 16 + kq * 4 + r) * 128 + n0 + j * 16 + lm] =
                    (bf16)acc[i][j][r];
}

// P[bz][n][m] = exp(q.k + RH + RW - 8), bf16; row sums -> lsum[bz][n]
__global__ __launch_bounds__(512, 1) void gemm3b_kernel(
    const bf16* __restrict__ qk, const bf16* __restrict__ rhwT,
    bf16* __restrict__ P, float* __restrict__ lsum, int gbase)
{
    __shared__ bf16 smem[66560];
    __shared__ float rs[256];
    // XCD-aware bijective swizzle (1024 blocks % 8 == 0)
    int flat = blockIdx.x + 16 * blockIdx.y + 256 * blockIdx.z;
    flat = (flat & 7) * 128 + (flat >> 3);
    const int bx = flat & 15, by = (flat >> 4) & 15, bz = flat >> 8;
    const int b = gbase + bz;
    const int tid = threadIdx.x;
    const int wid = tid >> 6;
    const int lane = tid & 63;
    const int wm = wid >> 2, wn = wid & 3;
    const int lm = lane & 15, kq = lane >> 4;
    const bf16* A = qk + ((size_t)b * 4096 + by * 256) * 512;        // q rows
    const bf16* Bm = qk + ((size_t)b * 4096 + bx * 256) * 512 + 256; // k rows
    f32x4 acc[8][4];
    gemm_core_256(A, 512, Bm, 512, 256, acc, smem, smem + 32768);
    // ---- positional terms
    bf16x2 rhv2[4];
    bf16x4 rwv[4][4];
    {
        const bf16* rbT = rhwT + ((size_t)b * 4096 + bx * 256) * 128;
#pragma unroll
        for (int j = 0; j < 4; ++j) {
            const bf16* cp = rbT + (size_t)(wn * 64 + j * 16 + lm) * 128;
            rhv2[j] = *(const bf16x2*)(cp + by * 4 + wm * 2);
#pragma unroll
            for (int ii = 0; ii < 4; ++ii)
                rwv[j][ii] = *(const bf16x4*)(cp + 64 + ii * 16 + kq * 4);
        }
    }
    if (tid < 256) rs[tid] = 0.f;
    __syncthreads();
    // exp + per-lane row partials
    float ps[8][4];
#pragma unroll
    for (int i = 0; i < 8; ++i)
#pragma unroll
        for (int r = 0; r < 4; ++r) {
            float s = 0.f;
#pragma unroll
            for (int j = 0; j < 4; ++j) {
                float sv = acc[i][j][r] + (float)rhv2[j][i >> 2]
                                        + (float)rwv[j][i & 3][r];
                float e = __expf(sv - 8.f);
                acc[i][j][r] = e;
                s += e;
            }
            ps[i][r] = s;
        }
#pragma unroll
    for (int msk = 1; msk < 16; msk <<= 1)
#pragma unroll
        for (int i = 0; i < 8; ++i)
#pragma unroll
            for (int r = 0; r < 4; ++r)
                ps[i][r] += __shfl_xor(ps[i][r], msk);
    if (lm == 0) {
#pragma unroll
        for (int i = 0; i < 8; ++i)
#pragma unroll
            for (int r = 0; r < 4; ++r)
                atomicAdd(&rs[wm * 128 + i * 16 + kq * 4 + r], ps[i][r]);
    }
    // stage exp(S) tile to LDS (stride 260)
#pragma unroll
    for (int i = 0; i < 8; ++i)
#pragma unroll
        for (int j = 0; j < 4; ++j)
#pragma unroll
            for (int r = 0; r < 4; ++r)
                smem[(wm * 128 + i * 16 + kq * 4 + r) * 260
                     + wn * 64 + j * 16 + lm] = (bf16)acc[i][j][r];
    __syncthreads();
    // coalesced store: 16 x 16B per thread, wave writes 1KB contiguous
    {
        bf16* Pb = P + ((size_t)bz * 4096 + by * 256) * 4096 + bx * 256;
        const char* Sl = (const char*)smem;
#pragma unroll
        for (int c = 0; c < 16; ++c) {
            int o = c * 8192 + tid * 16;
            int row = o >> 9, colb = o & 511;
            bf16x8 v = *(const bf16x8*)(Sl + row * 520 + colb);
            *(bf16x8*)((char*)Pb + (size_t)row * 8192 + colb) = v;
        }
    }
    if (tid < 256)
        atomicAdd(&lsum[(size_t)bz * 4096 + by * 256 + tid], rs[tid]);
}

// split-K=4 PV on the 256^2 core: all 256 cols per block.
__global__ __launch_bounds__(512, 1) void gemm4b_kernel(
    const bf16* __restrict__ P, const bf16* __restrict__ v_cm,
    bf16* __restrict__ pacc, int gbase)
{
    __shared__ bf16 smem[66560];
    int flat = blockIdx.x + 16 * blockIdx.y + 64 * blockIdx.z;
    flat = (flat & 7) * 32 + (flat >> 3);
    const int by = flat & 15, kc = (flat >> 4) & 3, bz = flat >> 6;
    const int b = gbase + bz;
    const bf16* A = P + ((size_t)bz * 4096 + by * 256) * 4096 + kc * 1024;
    const bf16* Bm = v_cm + (size_t)b * 256 * 4096 + kc * 1024;
    f32x4 acc[8][4];
    gemm_core_256(A, 4096, Bm, 4096, 1024, acc, smem, smem + 32768);
    const int tid = threadIdx.x, lane = tid & 63, wid = tid >> 6;
    const int wm = wid >> 2, wn = wid & 3, lm = lane & 15, kq = lane >> 4;
#pragma unroll
    for (int i = 0; i < 8; ++i)
#pragma unroll
        for (int j = 0; j < 4; ++j)
#pragma unroll
            for (int r = 0; r < 4; ++r)
                smem[(wm * 128 + i * 16 + kq * 4 + r) * 260
                     + wn * 64 + j * 16 + lm] = (bf16)acc[i][j][r];
    __syncthreads();
    {
        bf16* ob = pacc + ((size_t)kc * 16384 + bz * 4096 + by * 256) * 256;
        const char* Sl = (const char*)smem;
#pragma unroll
        for (int c = 0; c < 16; ++c) {
            int o = c * 8192 + tid * 16;
            int row = o >> 9, colb = o & 511;
            bf16x8 v = *(const bf16x8*)(Sl + row * 520 + colb);
            *(bf16x8*)((char*)ob + (size_t)row * 512 + colb) = v;
        }
    }
}

// out_t[(gbase*4096)+row][c] = (sum_kc pacc[kc][row][c]) / lsum[row]
__global__ __launch_bounds__(256) void reduce4_kernel(
    const bf16* __restrict__ pacc, const float* __restrict__ lsum,
    bf16* __restrict__ out_t, int gbase)
{
    int t = blockIdx.x * 256 + threadIdx.x;   // 524288 threads
    int row = t >> 5;                          // 0..16383
    int c0 = (t & 31) * 8;
    bf16x8 p0 = *(const bf16x8*)(pacc + (size_t)row * 256 + c0);
    bf16x8 p1 = *(const bf16x8*)(pacc + (size_t)(16384 + row) * 256 + c0);
    bf16x8 p2 = *(const bf16x8*)(pacc + (size_t)(32768 + row) * 256 + c0);
    bf16x8 p3 = *(const bf16x8*)(pacc + (size_t)(49152 + row) * 256 + c0);
    float inv = 1.f / lsum[row];
    bf16x8 o;
#pragma unroll
    for (int e = 0; e < 8; ++e)
        o[e] = (bf16)((((float)p0[e] + (float)p1[e]) +
                       ((float)p2[e] + (float)p3[e])) * inv);
    *(bf16x8*)(out_t + ((size_t)gbase * 4096 + row) * 256 + c0) = o;
}

// d_out[b][d][n] = x[b][d][n] + silu(bn2( sum_c w2b[d][c]*out_t[b*4096+n][c] ))
__global__ __launch_bounds__(512, 1) void gemm5_kernel(
    const bf16* __restrict__ w2b, const bf16* __restrict__ out_t,
    const float* __restrict__ bn2s, const float* __restrict__ bn2h,
    const float* __restrict__ x, float* __restrict__ out)
{
    __shared__ bf16 smem[65536];
    int b = blockIdx.z;
    const bf16* A = w2b + (size_t)(blockIdx.y * 256) * 256;              // d rows
    const bf16* Bm = out_t + ((size_t)b * 4096 + blockIdx.x * 256) * 256; // n rows
    f32x4 acc[8][4];
    gemm_core_256(A, 256, Bm, 256, 256, acc, smem, smem + 32768);
    const int tid = threadIdx.x, lane = tid & 63, wid = tid >> 6;
    const int wm = wid >> 2, wn = wid & 3, lm = lane & 15, kq = lane >> 4;
#pragma unroll
    for (int i = 0; i < 8; ++i)
#pragma unroll
        for (int j = 0; j < 4; ++j)
#pragma unroll
            for (int r = 0; r < 4; ++r) {
                int d = blockIdx.y * 256 + wm * 128 + i * 16 + kq * 4 + r;
                int n = blockIdx.x * 256 + wn * 64 + j * 16 + lm;
                float h = bn2s[d] * acc[i][j][r] + bn2h[d];
                size_t gi = ((size_t)(b * 512 + d)) * 4096 + n;
                out[gi] = x[gi] + silu_f(h);
            }
}

// ------------------------------- launcher ----------------------------------

extern "C" void kernel_launch(void* const* d_in, const int* in_sizes, int n_in,
                              void* d_out, int out_size, void* d_ws, size_t ws_size,
                              hipStream_t stream)
{
    (void)in_sizes; (void)n_in; (void)out_size; (void)ws_size;
    const float* x     = (const float*)d_in[0];
    const float* cv1_w = (const float*)d_in[1];
    const float* bn1_g = (const float*)d_in[2];
    const float* bn1_b = (const float*)d_in[3];
    const float* bn1_m = (const float*)d_in[4];
    const float* bn1_v = (const float*)d_in[5];
    const float* q_w   = (const float*)d_in[6];
    const float* q_b   = (const float*)d_in[7];
    const float* k_w   = (const float*)d_in[8];
    const float* k_b   = (const float*)d_in[9];
    const float* v_w   = (const float*)d_in[10];
    const float* v_b   = (const float*)d_in[11];
    const float* e_w   = (const float*)d_in[12];
    const float* e_b   = (const float*)d_in[13];
    const float* rel_h = (const float*)d_in[14];
    const float* rel_w = (const float*)d_in[15];
    const float* cv2_w = (const float*)d_in[16];
    const float* bn2_g = (const float*)d_in[17];
    const float* bn2_b = (const float*)d_in[18];
    const float* bn2_m = (const float*)d_in[19];
    const float* bn2_v = (const float*)d_in[20];
    float* out = (float*)d_out;

    char* ws = (char*)d_ws;
    bf16* P     = (bf16*)(ws + 0);            // 128 MB [4][4096][4096]
    bf16* xt    = (bf16*)(ws + 0);            //  32 MB overlay
    bf16* x1t   = (bf16*)(ws + 33554432);     //  16 MB overlay
    bf16* v_nm  = (bf16*)(ws + 50331648);     //  16 MB overlay
    bf16* e_nm  = (bf16*)(ws + 67108864);     //  16 MB overlay
    bf16* qk    = (bf16*)(ws + 134217728);    //  32 MB [32768][512] (q|k)
    bf16* v_cm  = (bf16*)(ws + 167772160);    //  16 MB [8][256][4096]
    bf16* rhwT  = (bf16*)(ws + 184549376);    //   8 MB [8][4096][128]
    bf16* out_t = (bf16*)(ws + 192937984);    //  16 MB [32768][256]
    bf16* w1b   = (bf16*)(ws + 209715200);    // 256 KB
    bf16* wqkve = (bf16*)(ws + 209977344);    // 512 KB
    bf16* w2b   = (bf16*)(ws + 210501632);    // 256 KB
    bf16* posT  = (bf16*)(ws + 210763776);    //  64 KB [128][256]
    float* biasq= (float*)(ws + 210829312);   //   4 KB
    float* bn1s = (float*)(ws + 210833408);
    float* bn1h = (float*)(ws + 210834432);
    float* bn2s = (float*)(ws + 210835456);
    float* bn2h = (float*)(ws + 210837504);
    float* lsum = (float*)(ws + 210839552);   // 128 KB [2][4][4096] fp32
    // pacc (32 MB, [4][16384][256] bf16) lives in d_out: dead after reduce4,
    // and gemm5 (the only writer of d_out) runs strictly after.
    bf16* pacc  = (bf16*)d_out;

    prep_misc_kernel<<<2183, 256, 0, stream>>>(
        cv1_w, q_w, q_b, k_w, k_b, v_w, v_b, e_w, e_b, cv2_w,
        bn1_g, bn1_b, bn1_m, bn1_v, bn2_g, bn2_b, bn2_m, bn2_v,
        rel_h, rel_w,
        w1b, wqkve, w2b, posT, biasq, bn1s, bn1h, bn2s, bn2h);
    zero_lsum_kernel<<<128, 256, 0, stream>>>(lsum);
    transpose_x_kernel<<<dim3(64, 8, 8), 256, 0, stream>>>(x, xt);
    gemm1_kernel<<<dim3(2, 256), 256, 0, stream>>>(xt, w1b, bn1s, bn1h, x1t);
    gemm2_kernel<<<dim3(4, 128), 512, 0, stream>>>(x1t, wqkve, biasq, qk, v_nm, e_nm);
    gemm_rhw_kernel<<<dim3(32, 1, 8), 256, 0, stream>>>(posT, e_nm, rhwT);
    transpose_v_kernel<<<dim3(64, 4, 8), 256, 0, stream>>>(v_nm, v_cm);
    for (int g = 0; g < 2; ++g) {
        float* ls = lsum + (size_t)g * 4 * 4096;
        gemm3b_kernel<<<dim3(16, 16, 4), 512, 0, stream>>>(qk, rhwT, P, ls, g * 4);
        gemm4b_kernel<<<dim3(16, 4, 4), 512, 0, stream>>>(P, v_cm, pacc, g * 4);
        reduce4_kernel<<<2048, 256, 0, stream>>>(pacc, ls, out_t, g * 4);
    }
    gemm5_kernel<<<dim3(16, 2, 8), 512, 0, stream>>>(w2b, out_t, bn2s, bn2h, x, out);
}